// Round 1
// baseline (260.775 us; speedup 1.0000x reference)
//
#include <hip/hip_runtime.h>
#include <math.h>

// Problem constants
#define B_N 2
#define S_N 2048
#define DM  512
#define H_N 8
#define DH  64
#define NC  32     // number of chunks = S/64
#define CH  64     // chunk length

__device__ __forceinline__ float dot4(float4 a, float4 b) {
    return a.x*b.x + a.y*b.y + a.z*b.z + a.w*b.w;
}

// ---------------------------------------------------------------------------
// Kernel 1: fused QK+V projection.  C[m][n] = x[m][:] . W[n][:] + bias[n]
// M=4096 rows (b*S+t), N=1536 cols (0..511 q, 512..1023 k, 1024..1535 v).
// q,k get elu()+1.  Outputs written per-head: [b][h][t][d].
// 128x128 tile, 8x8 micro-tile, LDS staged transposed so compute reads are b128.
// ---------------------------------------------------------------------------
__global__ __launch_bounds__(256) void gemm_qkv(
    const float* __restrict__ x,
    const float* __restrict__ Wqk, const float* __restrict__ bqk,
    const float* __restrict__ Wv,  const float* __restrict__ bv,
    float* __restrict__ qp, float* __restrict__ kp, float* __restrict__ vp)
{
    __shared__ __align__(16) float Xs[16][132];
    __shared__ __align__(16) float Ws[16][132];
    const int tid = threadIdx.x;
    const int tx = tid & 15, ty = tid >> 4;
    const int n0 = blockIdx.x * 128;   // grid.x = 12
    const int m0 = blockIdx.y * 128;   // grid.y = 32

    const float* Wb; const float* bias; int nc0;
    if (n0 < 1024) { Wb = Wqk; bias = bqk; nc0 = n0; }
    else           { Wb = Wv;  bias = bv;  nc0 = n0 - 1024; }

    const int smi = tid >> 1;          // 0..127
    const int sk8 = (tid & 1) << 3;    // 0 or 8

    float c[8][8] = {};

    for (int k0 = 0; k0 < DM; k0 += 16) {
        float4 xa = *(const float4*)&x [(size_t)(m0 + smi) * DM + k0 + sk8];
        float4 xb = *(const float4*)&x [(size_t)(m0 + smi) * DM + k0 + sk8 + 4];
        float4 wa = *(const float4*)&Wb[(size_t)(nc0 + smi) * DM + k0 + sk8];
        float4 wb = *(const float4*)&Wb[(size_t)(nc0 + smi) * DM + k0 + sk8 + 4];
        __syncthreads();
        {
            float xs8[8] = {xa.x,xa.y,xa.z,xa.w,xb.x,xb.y,xb.z,xb.w};
            float ws8[8] = {wa.x,wa.y,wa.z,wa.w,wb.x,wb.y,wb.z,wb.w};
            #pragma unroll
            for (int l = 0; l < 8; l++) {
                Xs[sk8 + l][smi] = xs8[l];
                Ws[sk8 + l][smi] = ws8[l];
            }
        }
        __syncthreads();
        #pragma unroll
        for (int kk = 0; kk < 16; kk++) {
            float4 a0 = *(const float4*)&Xs[kk][ty * 8];
            float4 a1 = *(const float4*)&Xs[kk][ty * 8 + 4];
            float4 b0 = *(const float4*)&Ws[kk][tx * 8];
            float4 b1 = *(const float4*)&Ws[kk][tx * 8 + 4];
            float av[8] = {a0.x,a0.y,a0.z,a0.w,a1.x,a1.y,a1.z,a1.w};
            float bw[8] = {b0.x,b0.y,b0.z,b0.w,b1.x,b1.y,b1.z,b1.w};
            #pragma unroll
            for (int i = 0; i < 8; i++)
                #pragma unroll
                for (int j = 0; j < 8; j++)
                    c[i][j] += av[i] * bw[j];
        }
    }

    #pragma unroll
    for (int i = 0; i < 8; i++) {
        int m = m0 + ty * 8 + i;
        int bb = m >> 11;            // /S_N
        int t  = m & (S_N - 1);
        #pragma unroll
        for (int j = 0; j < 8; j++) {
            int n = n0 + tx * 8 + j;
            float val = c[i][j] + bias[nc0 + tx * 8 + j];
            if (n < 1024) val = (val > 0.f) ? (val + 1.f) : __expf(val);  // elu+1
            int nn; float* dst;
            if (n < 512)       { nn = n;        dst = qp; }
            else if (n < 1024) { nn = n - 512;  dst = kp; }
            else               { nn = n - 1024; dst = vp; }
            int h = nn >> 6, d = nn & 63;
            dst[(((size_t)bb * H_N + h) * S_N + t) * DH + d] = val;
        }
    }
}

// ---------------------------------------------------------------------------
// Kernel 2: per-chunk state sums.  A[c][d1][d2] = sum_t k[t][d1]*v[t][d2],
// z[c][d1] = sum_t k[t][d1].  One block per (b,h,chunk).
// ---------------------------------------------------------------------------
__global__ __launch_bounds__(256) void chunk_sums(
    const float* __restrict__ kp, const float* __restrict__ vp,
    float* __restrict__ Asum, float* __restrict__ zsum)
{
    __shared__ __align__(16) float kc[64 * 68];
    __shared__ __align__(16) float vc[64 * 68];
    const int blk = blockIdx.x;           // 0..511
    const size_t base = (size_t)(blk >> 5) * (size_t)S_N * 64 + (size_t)(blk & 31) * 64 * 64;
    const int tid = threadIdx.x;

    for (int idx = tid; idx < 4096; idx += 256) {
        int t = idx >> 6, d = idx & 63;
        kc[t * 68 + d] = kp[base + idx];
        vc[t * 68 + d] = vp[base + idx];
    }
    __syncthreads();

    const int d1 = tid >> 2;
    const int jb = (tid & 3) << 4;
    float4 acc0 = {0,0,0,0}, acc1 = {0,0,0,0}, acc2 = {0,0,0,0}, acc3 = {0,0,0,0};
    for (int t = 0; t < 64; t++) {
        float kv = kc[t * 68 + d1];
        const float4* vr = (const float4*)&vc[t * 68 + jb];
        float4 v0 = vr[0], v1 = vr[1], v2 = vr[2], v3 = vr[3];
        acc0.x += kv*v0.x; acc0.y += kv*v0.y; acc0.z += kv*v0.z; acc0.w += kv*v0.w;
        acc1.x += kv*v1.x; acc1.y += kv*v1.y; acc1.z += kv*v1.z; acc1.w += kv*v1.w;
        acc2.x += kv*v2.x; acc2.y += kv*v2.y; acc2.z += kv*v2.z; acc2.w += kv*v2.w;
        acc3.x += kv*v3.x; acc3.y += kv*v3.y; acc3.z += kv*v3.z; acc3.w += kv*v3.w;
    }
    float* ap = &Asum[(size_t)blk * 4096 + d1 * 64 + jb];
    ((float4*)ap)[0] = acc0; ((float4*)ap)[1] = acc1;
    ((float4*)ap)[2] = acc2; ((float4*)ap)[3] = acc3;

    if (tid < 64) {
        float z = 0.f;
        for (int t = 0; t < 64; t++) z += kc[t * 68 + tid];
        zsum[(size_t)blk * 64 + tid] = z;
    }
}

// ---------------------------------------------------------------------------
// Kernel 3: in-place exclusive prefix scan over chunks, per (b,h), per state
// element.  66560 independent lanes = 260 blocks x 256 threads.
// ---------------------------------------------------------------------------
__global__ __launch_bounds__(256) void scan_states(
    float* __restrict__ Asum, float* __restrict__ zsum)
{
    const int gid = blockIdx.x * 256 + threadIdx.x;   // 0..66559
    const int bh = gid / 4160;
    const int r  = gid % 4160;
    if (r < 4096) {
        size_t base = (size_t)bh * NC * 4096 + r;
        float acc = 0.f;
        for (int c = 0; c < NC; c++) {
            float tmp = Asum[base + (size_t)c * 4096];
            Asum[base + (size_t)c * 4096] = acc;
            acc += tmp;
        }
    } else {
        int d = r - 4096;
        size_t base = (size_t)bh * NC * 64 + d;
        float acc = 0.f;
        for (int c = 0; c < NC; c++) {
            float tmp = zsum[base + (size_t)c * 64];
            zsum[base + (size_t)c * 64] = acc;
            acc += tmp;
        }
    }
}

// ---------------------------------------------------------------------------
// Kernel 4: per-chunk attention.  One block per (b,h,chunk).
//   num[t] = q_t @ Sprev + sum_{u<=t} (q_t.k_u) v_u
//   nu[t]  = q_t . zprev + sum_{u<=t} (q_t.k_u)
//   ctx[t] = num[t] / nu[t]   written as [b][t][h][d]
// LDS buffers are reused across phases to stay under 64 KB.
// ---------------------------------------------------------------------------
__global__ __launch_bounds__(256) void attn_chunk(
    const float* __restrict__ qp, const float* __restrict__ kp,
    const float* __restrict__ vp, const float* __restrict__ Sprev,
    const float* __restrict__ zprev, float* __restrict__ ctx)
{
    __shared__ __align__(16) float A_[64 * 68];   // q, later v
    __shared__ __align__(16) float Bb[64 * 68];   // k, later Sprev
    __shared__ __align__(16) float Sc[64 * 68];   // scores
    __shared__ __align__(16) float zp[64];
    __shared__ float nupart[64][4];

    const int blk = blockIdx.x;           // 0..511
    const int bh = blk >> 5, c = blk & 31;
    const int b = bh >> 3, h = bh & 7;
    const size_t base = (size_t)bh * S_N * 64 + (size_t)c * 64 * 64;
    const int tid = threadIdx.x;
    const int tl = tid >> 2;              // row t within chunk
    const int jb = (tid & 3) << 4;        // 16-col strip

    for (int idx = tid; idx < 4096; idx += 256) {
        int t = idx >> 6, d = idx & 63;
        A_[t * 68 + d] = qp[base + idx];
        Bb[t * 68 + d] = kp[base + idx];
    }
    if (tid < 64) zp[tid] = zprev[(size_t)blk * 64 + tid];
    __syncthreads();

    // preload my q row into registers (static indexing only)
    float4 qr[16];
    #pragma unroll
    for (int d4 = 0; d4 < 16; d4++) qr[d4] = *(const float4*)&A_[tl * 68 + 4 * d4];

    // phase 1: scores (causal) + nu partials
    float nup = 0.f;
    #pragma unroll
    for (int j = 0; j < 16; j++) {
        int u = jb + j;
        float s = 0.f;
        if (u <= tl) {
            const float4* kr = (const float4*)&Bb[u * 68];
            #pragma unroll
            for (int d4 = 0; d4 < 16; d4++) s += dot4(qr[d4], kr[d4]);
        }
        Sc[tl * 68 + u] = s;
        nup += s;
    }
    // inter part of nu: q[jb..jb+15] . zp[jb..jb+15]
    #pragma unroll
    for (int l = 0; l < 4; l++) {
        float4 qq = *(const float4*)&A_[tl * 68 + jb + 4 * l];
        float4 zz = *(const float4*)&zp[jb + 4 * l];
        nup += dot4(qq, zz);
    }
    nupart[tl][tid & 3] = nup;
    __syncthreads();

    // overwrite k with Sprev
    for (int idx = tid; idx < 4096; idx += 256)
        Bb[(idx >> 6) * 68 + (idx & 63)] = Sprev[(size_t)blk * 4096 + idx];
    __syncthreads();

    // inter: acc[j] = sum_d1 q[tl][d1] * Sprev[d1][jb+j]
    float4 acc0 = {0,0,0,0}, acc1 = {0,0,0,0}, acc2 = {0,0,0,0}, acc3 = {0,0,0,0};
    for (int d1 = 0; d1 < 64; d1++) {
        float qv = A_[tl * 68 + d1];
        const float4* sp = (const float4*)&Bb[d1 * 68 + jb];
        float4 s0 = sp[0], s1 = sp[1], s2 = sp[2], s3 = sp[3];
        acc0.x += qv*s0.x; acc0.y += qv*s0.y; acc0.z += qv*s0.z; acc0.w += qv*s0.w;
        acc1.x += qv*s1.x; acc1.y += qv*s1.y; acc1.z += qv*s1.z; acc1.w += qv*s1.w;
        acc2.x += qv*s2.x; acc2.y += qv*s2.y; acc2.z += qv*s2.z; acc2.w += qv*s2.w;
        acc3.x += qv*s3.x; acc3.y += qv*s3.y; acc3.z += qv*s3.z; acc3.w += qv*s3.w;
    }
    __syncthreads();

    // overwrite q with v
    for (int idx = tid; idx < 4096; idx += 256)
        A_[(idx >> 6) * 68 + (idx & 63)] = vp[base + idx];
    __syncthreads();

    // intra: acc[j] += sum_u Sc[tl][u] * v[u][jb+j]   (Sc=0 above diagonal)
    for (int u = 0; u < 64; u++) {
        float sv = Sc[tl * 68 + u];
        const float4* vr = (const float4*)&A_[u * 68 + jb];
        float4 v0 = vr[0], v1 = vr[1], v2 = vr[2], v3 = vr[3];
        acc0.x += sv*v0.x; acc0.y += sv*v0.y; acc0.z += sv*v0.z; acc0.w += sv*v0.w;
        acc1.x += sv*v1.x; acc1.y += sv*v1.y; acc1.z += sv*v1.z; acc1.w += sv*v1.w;
        acc2.x += sv*v2.x; acc2.y += sv*v2.y; acc2.z += sv*v2.z; acc2.w += sv*v2.w;
        acc3.x += sv*v3.x; acc3.y += sv*v3.y; acc3.z += sv*v3.z; acc3.w += sv*v3.w;
    }

    float nu = nupart[tl][0] + nupart[tl][1] + nupart[tl][2] + nupart[tl][3];
    float inv = 1.f / nu;
    size_t obase = (((size_t)b * S_N + (size_t)c * 64 + tl) * H_N + h) * DH + jb;
    float4 r0 = {acc0.x*inv, acc0.y*inv, acc0.z*inv, acc0.w*inv};
    float4 r1 = {acc1.x*inv, acc1.y*inv, acc1.z*inv, acc1.w*inv};
    float4 r2 = {acc2.x*inv, acc2.y*inv, acc2.z*inv, acc2.w*inv};
    float4 r3 = {acc3.x*inv, acc3.y*inv, acc3.z*inv, acc3.w*inv};
    *(float4*)&ctx[obase + 0]  = r0;
    *(float4*)&ctx[obase + 4]  = r1;
    *(float4*)&ctx[obase + 8]  = r2;
    *(float4*)&ctx[obase + 12] = r3;
}

// ---------------------------------------------------------------------------
// Kernel 5: output projection.  out[m][n] = ctx[m][:] . Wo[n][:] + bo[n]
// 64x128 tile, 4x8 micro-tile.
// ---------------------------------------------------------------------------
__global__ __launch_bounds__(256) void gemm_out(
    const float* __restrict__ ctx, const float* __restrict__ Wo,
    const float* __restrict__ bo, float* __restrict__ out)
{
    __shared__ __align__(16) float Xs[16][68];
    __shared__ __align__(16) float Ws[16][132];
    const int tid = threadIdx.x;
    const int tx = tid & 15, ty = tid >> 4;
    const int n0 = blockIdx.x * 128;   // grid.x = 4
    const int m0 = blockIdx.y * 64;    // grid.y = 64

    const int xmi = tid >> 2, xk4 = (tid & 3) << 2;
    const int wni = tid >> 1, wk8 = (tid & 1) << 3;

    float c[4][8] = {};

    for (int k0 = 0; k0 < DM; k0 += 16) {
        float4 xa = *(const float4*)&ctx[(size_t)(m0 + xmi) * DM + k0 + xk4];
        float4 wa = *(const float4*)&Wo [(size_t)(n0 + wni) * DM + k0 + wk8];
        float4 wb = *(const float4*)&Wo [(size_t)(n0 + wni) * DM + k0 + wk8 + 4];
        __syncthreads();
        {
            float xs4[4] = {xa.x,xa.y,xa.z,xa.w};
            float ws8[8] = {wa.x,wa.y,wa.z,wa.w,wb.x,wb.y,wb.z,wb.w};
            #pragma unroll
            for (int l = 0; l < 4; l++) Xs[xk4 + l][xmi] = xs4[l];
            #pragma unroll
            for (int l = 0; l < 8; l++) Ws[wk8 + l][wni] = ws8[l];
        }
        __syncthreads();
        #pragma unroll
        for (int kk = 0; kk < 16; kk++) {
            float4 a  = *(const float4*)&Xs[kk][ty * 4];
            float4 b0 = *(const float4*)&Ws[kk][tx * 8];
            float4 b1 = *(const float4*)&Ws[kk][tx * 8 + 4];
            float av[4] = {a.x,a.y,a.z,a.w};
            float bw[8] = {b0.x,b0.y,b0.z,b0.w,b1.x,b1.y,b1.z,b1.w};
            #pragma unroll
            for (int i = 0; i < 4; i++)
                #pragma unroll
                for (int j = 0; j < 8; j++)
                    c[i][j] += av[i] * bw[j];
        }
    }

    #pragma unroll
    for (int i = 0; i < 4; i++) {
        int m = m0 + ty * 4 + i;
        #pragma unroll
        for (int j = 0; j < 8; j++) {
            int n = n0 + tx * 8 + j;
            out[(size_t)m * DM + n] = c[i][j] + bo[n];
        }
    }
}

// ---------------------------------------------------------------------------
extern "C" void kernel_launch(void* const* d_in, const int* in_sizes, int n_in,
                              void* d_out, int out_size, void* d_ws, size_t ws_size,
                              hipStream_t stream)
{
    const float* x   = (const float*)d_in[0];
    const float* Wqk = (const float*)d_in[1];
    const float* bqk = (const float*)d_in[2];
    const float* Wv  = (const float*)d_in[3];
    const float* bv  = (const float*)d_in[4];
    const float* Wo  = (const float*)d_in[5];
    const float* bo  = (const float*)d_in[6];
    float* out = (float*)d_out;

    float* ws = (float*)d_ws;
    const size_t NTOK = (size_t)B_N * S_N * DM;   // 2,097,152
    float* qp   = ws;
    float* kp   = qp  + NTOK;
    float* vp   = kp  + NTOK;
    float* ctxp = vp  + NTOK;
    float* Asum = ctxp + NTOK;                    // B*H*NC*64*64 = NTOK
    float* zsum = Asum + NTOK;                    // B*H*NC*64 = 32768

    gemm_qkv  <<<dim3(12, 32), 256, 0, stream>>>(x, Wqk, bqk, Wv, bv, qp, kp, vp);
    chunk_sums<<<dim3(512),    256, 0, stream>>>(kp, vp, Asum, zsum);
    scan_states<<<dim3(260),   256, 0, stream>>>(Asum, zsum);
    attn_chunk<<<dim3(512),    256, 0, stream>>>(qp, kp, vp, Asum, zsum, ctxp);
    gemm_out  <<<dim3(4, 64),  256, 0, stream>>>(ctxp, Wo, bo, out);
}

// Round 2
// 142.105 us; speedup vs baseline: 1.8351x; 1.8351x over previous
//
#include <hip/hip_runtime.h>
#include <math.h>

// Problem constants
#define B_N 2
#define S_N 2048
#define DM  512
#define H_N 8
#define DH  64
#define NC  32     // number of chunks = S/64
#define CH  64     // chunk length

typedef __bf16 bf16x8 __attribute__((ext_vector_type(8)));
typedef float  f32x4  __attribute__((ext_vector_type(4)));

__device__ __forceinline__ float dot4(float4 a, float4 b) {
    return a.x*b.x + a.y*b.y + a.z*b.z + a.w*b.w;
}

__device__ __forceinline__ unsigned short f2bf(float f) {
    unsigned int u = __float_as_uint(f);
    u += 0x7FFFu + ((u >> 16) & 1u);          // round-to-nearest-even
    return (unsigned short)(u >> 16);
}

__device__ __forceinline__ void gload16(const void* g, void* l) {
    __builtin_amdgcn_global_load_lds(
        (const __attribute__((address_space(1))) unsigned int*)g,
        (__attribute__((address_space(3))) unsigned int*)l, 16, 0, 0);
}

// ---------------------------------------------------------------------------
// Kernel 0: fp32 -> bf16 conversion of x, Wqk, Wv, Wo.  One float4 per thread.
// ---------------------------------------------------------------------------
__global__ __launch_bounds__(256) void convert_bf16(
    const float* __restrict__ x,  const float* __restrict__ wqk,
    const float* __restrict__ wv, const float* __restrict__ wo,
    unsigned short* __restrict__ xb,  unsigned short* __restrict__ wqkb,
    unsigned short* __restrict__ wvb, unsigned short* __restrict__ wob)
{
    int gid = blockIdx.x * 256 + threadIdx.x;   // 0..786431 float4 units
    const float* src; unsigned short* dst; int off;
    if (gid < 524288)      { src = x;   dst = xb;   off = gid; }
    else if (gid < 655360) { src = wqk; dst = wqkb; off = gid - 524288; }
    else if (gid < 720896) { src = wv;  dst = wvb;  off = gid - 655360; }
    else                   { src = wo;  dst = wob;  off = gid - 720896; }
    float4 v = ((const float4*)src)[off];
    ushort4 r; r.x = f2bf(v.x); r.y = f2bf(v.y); r.z = f2bf(v.z); r.w = f2bf(v.w);
    ((ushort4*)dst)[off] = r;
}

// ---------------------------------------------------------------------------
// Kernel 1: fused QK+V projection via bf16 MFMA.
// C[m][n] = x[m][:] . W[n][:] + bias[n];  q,k get elu+1; scatter per-head.
// 128x128 tile, 4 waves (2x2), each wave 64x64 = 4x4 MFMAs of 16x16x32.
// global_load_lds width-16 staging into unpadded [row][32] bf16 LDS tiles.
// ---------------------------------------------------------------------------
__global__ __launch_bounds__(256) void gemm_qkv_mfma(
    const unsigned short* __restrict__ xb,
    const unsigned short* __restrict__ Wqkb,
    const unsigned short* __restrict__ Wvb,
    const float* __restrict__ bqk, const float* __restrict__ bv,
    float* __restrict__ qp, float* __restrict__ kp, float* __restrict__ vp)
{
    __shared__ unsigned short Alds[128 * 32];
    __shared__ unsigned short Blds[128 * 32];
    const int tid = threadIdx.x;
    const int w = tid >> 6, l = tid & 63;
    const int wm = w >> 1, wn = w & 1;
    const int lane15 = l & 15, quad = l >> 4;
    const int n0 = blockIdx.x * 128;   // grid.x = 12
    const int m0 = blockIdx.y * 128;   // grid.y = 32

    const unsigned short* Wb; const float* bias; int nc0; int isqk;
    if (n0 < 1024) { Wb = Wqkb; bias = bqk; nc0 = n0;        isqk = 1; }
    else           { Wb = Wvb;  bias = bv;  nc0 = n0 - 1024; isqk = 0; }

    const int srow = w * 16 + (l >> 2);   // staging row 0..63 (call adds +64)
    const int skof = (l & 3) << 3;        // k offset within 32: 0,8,16,24

    f32x4 acc[4][4];
    #pragma unroll
    for (int i = 0; i < 4; i++)
        #pragma unroll
        for (int j = 0; j < 4; j++) acc[i][j] = (f32x4){0.f, 0.f, 0.f, 0.f};

    for (int k0 = 0; k0 < DM; k0 += 32) {
        __syncthreads();
        gload16(&xb[(size_t)(m0 + srow) * DM + k0 + skof],       (char*)Alds + w * 1024);
        gload16(&xb[(size_t)(m0 + 64 + srow) * DM + k0 + skof],  (char*)Alds + 4096 + w * 1024);
        gload16(&Wb[(size_t)(nc0 + srow) * DM + k0 + skof],      (char*)Blds + w * 1024);
        gload16(&Wb[(size_t)(nc0 + 64 + srow) * DM + k0 + skof], (char*)Blds + 4096 + w * 1024);
        __syncthreads();

        bf16x8 af[4], bfr[4];
        #pragma unroll
        for (int i = 0; i < 4; i++) {
            af[i]  = *(bf16x8*)&Alds[(wm * 64 + i * 16 + lane15) * 32 + quad * 8];
            bfr[i] = *(bf16x8*)&Blds[(wn * 64 + i * 16 + lane15) * 32 + quad * 8];
        }
        #pragma unroll
        for (int i = 0; i < 4; i++)
            #pragma unroll
            for (int j = 0; j < 4; j++)
                acc[i][j] = __builtin_amdgcn_mfma_f32_16x16x32_bf16(af[i], bfr[j], acc[i][j], 0, 0, 0);
    }

    // block-uniform destination select (n0 is a multiple of 128; q/k/v bounds are too)
    float* dst; int nbase;
    if (n0 < 512)       { dst = qp; nbase = n0; }
    else if (n0 < 1024) { dst = kp; nbase = n0 - 512; }
    else                { dst = vp; nbase = n0 - 1024; }

    #pragma unroll
    for (int i = 0; i < 4; i++) {
        #pragma unroll
        for (int rg = 0; rg < 4; rg++) {
            int m = m0 + wm * 64 + i * 16 + quad * 4 + rg;
            int bb = m >> 11;
            int t  = m & (S_N - 1);
            #pragma unroll
            for (int j = 0; j < 4; j++) {
                int ncol = wn * 64 + j * 16 + lane15;      // 0..127 within tile
                float val = acc[i][j][rg] + bias[nc0 + ncol];
                if (isqk) val = (val > 0.f) ? (val + 1.f) : __expf(val);  // elu+1
                int nn = nbase + ncol;                     // 0..511
                int h = nn >> 6, d = nn & 63;
                dst[(((size_t)bb * H_N + h) * S_N + t) * DH + d] = val;
            }
        }
    }
}

// ---------------------------------------------------------------------------
// Kernel 2: per-chunk state sums.  A[c][d1][d2] = sum_t k[t][d1]*v[t][d2],
// z[c][d1] = sum_t k[t][d1].  One block per (b,h,chunk).
// ---------------------------------------------------------------------------
__global__ __launch_bounds__(256) void chunk_sums(
    const float* __restrict__ kp, const float* __restrict__ vp,
    float* __restrict__ Asum, float* __restrict__ zsum)
{
    __shared__ __align__(16) float kc[64 * 68];
    __shared__ __align__(16) float vc[64 * 68];
    const int blk = blockIdx.x;           // 0..511
    const size_t base = (size_t)(blk >> 5) * (size_t)S_N * 64 + (size_t)(blk & 31) * 64 * 64;
    const int tid = threadIdx.x;

    for (int idx = tid; idx < 4096; idx += 256) {
        int t = idx >> 6, d = idx & 63;
        kc[t * 68 + d] = kp[base + idx];
        vc[t * 68 + d] = vp[base + idx];
    }
    __syncthreads();

    const int d1 = tid >> 2;
    const int jb = (tid & 3) << 4;
    float4 acc0 = {0,0,0,0}, acc1 = {0,0,0,0}, acc2 = {0,0,0,0}, acc3 = {0,0,0,0};
    for (int t = 0; t < 64; t++) {
        float kv = kc[t * 68 + d1];
        const float4* vr = (const float4*)&vc[t * 68 + jb];
        float4 v0 = vr[0], v1 = vr[1], v2 = vr[2], v3 = vr[3];
        acc0.x += kv*v0.x; acc0.y += kv*v0.y; acc0.z += kv*v0.z; acc0.w += kv*v0.w;
        acc1.x += kv*v1.x; acc1.y += kv*v1.y; acc1.z += kv*v1.z; acc1.w += kv*v1.w;
        acc2.x += kv*v2.x; acc2.y += kv*v2.y; acc2.z += kv*v2.z; acc2.w += kv*v2.w;
        acc3.x += kv*v3.x; acc3.y += kv*v3.y; acc3.z += kv*v3.z; acc3.w += kv*v3.w;
    }
    float* ap = &Asum[(size_t)blk * 4096 + d1 * 64 + jb];
    ((float4*)ap)[0] = acc0; ((float4*)ap)[1] = acc1;
    ((float4*)ap)[2] = acc2; ((float4*)ap)[3] = acc3;

    if (tid < 64) {
        float z = 0.f;
        for (int t = 0; t < 64; t++) z += kc[t * 68 + tid];
        zsum[(size_t)blk * 64 + tid] = z;
    }
}

// ---------------------------------------------------------------------------
// Kernel 3: in-place exclusive prefix scan over chunks, per (b,h), per state
// element.  66560 independent lanes = 260 blocks x 256 threads.
// ---------------------------------------------------------------------------
__global__ __launch_bounds__(256) void scan_states(
    float* __restrict__ Asum, float* __restrict__ zsum)
{
    const int gid = blockIdx.x * 256 + threadIdx.x;   // 0..66559
    const int bh = gid / 4160;
    const int r  = gid % 4160;
    if (r < 4096) {
        size_t base = (size_t)bh * NC * 4096 + r;
        float acc = 0.f;
        for (int c = 0; c < NC; c++) {
            float tmp = Asum[base + (size_t)c * 4096];
            Asum[base + (size_t)c * 4096] = acc;
            acc += tmp;
        }
    } else {
        int d = r - 4096;
        size_t base = (size_t)bh * NC * 64 + d;
        float acc = 0.f;
        for (int c = 0; c < NC; c++) {
            float tmp = zsum[base + (size_t)c * 64];
            zsum[base + (size_t)c * 64] = acc;
            acc += tmp;
        }
    }
}

// ---------------------------------------------------------------------------
// Kernel 4: per-chunk attention (fp32).  One block per (b,h,chunk).
//   num[t] = q_t @ Sprev + sum_{u<=t} (q_t.k_u) v_u
//   nu[t]  = q_t . zprev + sum_{u<=t} (q_t.k_u)
//   ctx[t] = num[t] / nu[t]   written as bf16 in [b][t][h][d] (= [m][DM]).
// ---------------------------------------------------------------------------
__global__ __launch_bounds__(256) void attn_chunk(
    const float* __restrict__ qp, const float* __restrict__ kp,
    const float* __restrict__ vp, const float* __restrict__ Sprev,
    const float* __restrict__ zprev, unsigned short* __restrict__ ctxb)
{
    __shared__ __align__(16) float A_[64 * 68];   // q, later v
    __shared__ __align__(16) float Bb[64 * 68];   // k, later Sprev
    __shared__ __align__(16) float Sc[64 * 68];   // scores
    __shared__ __align__(16) float zp[64];
    __shared__ float nupart[64][4];

    const int blk = blockIdx.x;           // 0..511
    const int bh = blk >> 5, c = blk & 31;
    const int b = bh >> 3, h = bh & 7;
    const size_t base = (size_t)bh * S_N * 64 + (size_t)c * 64 * 64;
    const int tid = threadIdx.x;
    const int tl = tid >> 2;              // row t within chunk
    const int jb = (tid & 3) << 4;        // 16-col strip

    for (int idx = tid; idx < 4096; idx += 256) {
        int t = idx >> 6, d = idx & 63;
        A_[t * 68 + d] = qp[base + idx];
        Bb[t * 68 + d] = kp[base + idx];
    }
    if (tid < 64) zp[tid] = zprev[(size_t)blk * 64 + tid];
    __syncthreads();

    float4 qr[16];
    #pragma unroll
    for (int d4 = 0; d4 < 16; d4++) qr[d4] = *(const float4*)&A_[tl * 68 + 4 * d4];

    // phase 1: scores (causal) + nu partials
    float nup = 0.f;
    #pragma unroll
    for (int j = 0; j < 16; j++) {
        int u = jb + j;
        float s = 0.f;
        if (u <= tl) {
            const float4* kr = (const float4*)&Bb[u * 68];
            #pragma unroll
            for (int d4 = 0; d4 < 16; d4++) s += dot4(qr[d4], kr[d4]);
        }
        Sc[tl * 68 + u] = s;
        nup += s;
    }
    #pragma unroll
    for (int lq = 0; lq < 4; lq++) {
        float4 qq = *(const float4*)&A_[tl * 68 + jb + 4 * lq];
        float4 zz = *(const float4*)&zp[jb + 4 * lq];
        nup += dot4(qq, zz);
    }
    nupart[tl][tid & 3] = nup;
    __syncthreads();

    // overwrite k with Sprev
    for (int idx = tid; idx < 4096; idx += 256)
        Bb[(idx >> 6) * 68 + (idx & 63)] = Sprev[(size_t)blk * 4096 + idx];
    __syncthreads();

    // inter: acc[j] = sum_d1 q[tl][d1] * Sprev[d1][jb+j]
    float4 acc0 = {0,0,0,0}, acc1 = {0,0,0,0}, acc2 = {0,0,0,0}, acc3 = {0,0,0,0};
    for (int d1 = 0; d1 < 64; d1++) {
        float qv = A_[tl * 68 + d1];
        const float4* sp = (const float4*)&Bb[d1 * 68 + jb];
        float4 s0 = sp[0], s1 = sp[1], s2 = sp[2], s3 = sp[3];
        acc0.x += qv*s0.x; acc0.y += qv*s0.y; acc0.z += qv*s0.z; acc0.w += qv*s0.w;
        acc1.x += qv*s1.x; acc1.y += qv*s1.y; acc1.z += qv*s1.z; acc1.w += qv*s1.w;
        acc2.x += qv*s2.x; acc2.y += qv*s2.y; acc2.z += qv*s2.z; acc2.w += qv*s2.w;
        acc3.x += qv*s3.x; acc3.y += qv*s3.y; acc3.z += qv*s3.z; acc3.w += qv*s3.w;
    }
    __syncthreads();

    // overwrite q with v
    for (int idx = tid; idx < 4096; idx += 256)
        A_[(idx >> 6) * 68 + (idx & 63)] = vp[base + idx];
    __syncthreads();

    // intra: acc[j] += sum_u Sc[tl][u] * v[u][jb+j]   (Sc=0 above diagonal)
    for (int u = 0; u < 64; u++) {
        float sv = Sc[tl * 68 + u];
        const float4* vr = (const float4*)&A_[u * 68 + jb];
        float4 v0 = vr[0], v1 = vr[1], v2 = vr[2], v3 = vr[3];
        acc0.x += sv*v0.x; acc0.y += sv*v0.y; acc0.z += sv*v0.z; acc0.w += sv*v0.w;
        acc1.x += sv*v1.x; acc1.y += sv*v1.y; acc1.z += sv*v1.z; acc1.w += sv*v1.w;
        acc2.x += sv*v2.x; acc2.y += sv*v2.y; acc2.z += sv*v2.z; acc2.w += sv*v2.w;
        acc3.x += sv*v3.x; acc3.y += sv*v3.y; acc3.z += sv*v3.z; acc3.w += sv*v3.w;
    }

    float nu = nupart[tl][0] + nupart[tl][1] + nupart[tl][2] + nupart[tl][3];
    float inv = 1.f / nu;
    // ctx layout: [b][t][h][d] == row-major [m][DM] with m=b*S+t, col=h*64+d
    size_t obase = (((size_t)b * S_N + (size_t)c * 64 + tl) * DM) + (size_t)h * DH + jb;
    ushort4 r0 = {f2bf(acc0.x*inv), f2bf(acc0.y*inv), f2bf(acc0.z*inv), f2bf(acc0.w*inv)};
    ushort4 r1 = {f2bf(acc1.x*inv), f2bf(acc1.y*inv), f2bf(acc1.z*inv), f2bf(acc1.w*inv)};
    ushort4 r2 = {f2bf(acc2.x*inv), f2bf(acc2.y*inv), f2bf(acc2.z*inv), f2bf(acc2.w*inv)};
    ushort4 r3 = {f2bf(acc3.x*inv), f2bf(acc3.y*inv), f2bf(acc3.z*inv), f2bf(acc3.w*inv)};
    *(ushort4*)&ctxb[obase + 0]  = r0;
    *(ushort4*)&ctxb[obase + 4]  = r1;
    *(ushort4*)&ctxb[obase + 8]  = r2;
    *(ushort4*)&ctxb[obase + 12] = r3;
}

// ---------------------------------------------------------------------------
// Kernel 5: output projection via bf16 MFMA.  out[m][n] = ctx[m][:].Wo[n][:] + bo[n]
// 64x128 tile, 4 waves (2x2), each wave 32x64 = 2x4 MFMAs.
// ---------------------------------------------------------------------------
__global__ __launch_bounds__(256) void gemm_out_mfma(
    const unsigned short* __restrict__ ctxb,
    const unsigned short* __restrict__ Wob,
    const float* __restrict__ bo, float* __restrict__ out)
{
    __shared__ unsigned short Alds[64 * 32];
    __shared__ unsigned short Blds[128 * 32];
    const int tid = threadIdx.x;
    const int w = tid >> 6, l = tid & 63;
    const int wm = w >> 1, wn = w & 1;
    const int lane15 = l & 15, quad = l >> 4;
    const int n0 = blockIdx.x * 128;   // grid.x = 4
    const int m0 = blockIdx.y * 64;    // grid.y = 64

    const int srow = w * 16 + (l >> 2);
    const int skof = (l & 3) << 3;

    f32x4 acc[2][4];
    #pragma unroll
    for (int i = 0; i < 2; i++)
        #pragma unroll
        for (int j = 0; j < 4; j++) acc[i][j] = (f32x4){0.f, 0.f, 0.f, 0.f};

    for (int k0 = 0; k0 < DM; k0 += 32) {
        __syncthreads();
        gload16(&ctxb[(size_t)(m0 + srow) * DM + k0 + skof],      (char*)Alds + w * 1024);
        gload16(&Wob[(size_t)(n0 + srow) * DM + k0 + skof],       (char*)Blds + w * 1024);
        gload16(&Wob[(size_t)(n0 + 64 + srow) * DM + k0 + skof],  (char*)Blds + 4096 + w * 1024);
        __syncthreads();

        bf16x8 af[2], bfr[4];
        #pragma unroll
        for (int i = 0; i < 2; i++)
            af[i] = *(bf16x8*)&Alds[(wm * 32 + i * 16 + lane15) * 32 + quad * 8];
        #pragma unroll
        for (int j = 0; j < 4; j++)
            bfr[j] = *(bf16x8*)&Blds[(wn * 64 + j * 16 + lane15) * 32 + quad * 8];
        #pragma unroll
        for (int i = 0; i < 2; i++)
            #pragma unroll
            for (int j = 0; j < 4; j++)
                acc[i][j] = __builtin_amdgcn_mfma_f32_16x16x32_bf16(af[i], bfr[j], acc[i][j], 0, 0, 0);
    }

    #pragma unroll
    for (int i = 0; i < 2; i++) {
        #pragma unroll
        for (int rg = 0; rg < 4; rg++) {
            int m = m0 + wm * 32 + i * 16 + quad * 4 + rg;
            #pragma unroll
            for (int j = 0; j < 4; j++) {
                int n = n0 + wn * 64 + j * 16 + lane15;
                out[(size_t)m * DM + n] = acc[i][j][rg] + bo[n];
            }
        }
    }
}

// ---------------------------------------------------------------------------
extern "C" void kernel_launch(void* const* d_in, const int* in_sizes, int n_in,
                              void* d_out, int out_size, void* d_ws, size_t ws_size,
                              hipStream_t stream)
{
    const float* x   = (const float*)d_in[0];
    const float* Wqk = (const float*)d_in[1];
    const float* bqk = (const float*)d_in[2];
    const float* Wv  = (const float*)d_in[3];
    const float* bv  = (const float*)d_in[4];
    const float* Wo  = (const float*)d_in[5];
    const float* bo  = (const float*)d_in[6];
    float* out = (float*)d_out;

    float* ws = (float*)d_ws;
    const size_t NTOK = (size_t)B_N * S_N * DM;   // 2,097,152
    float* qp   = ws;
    float* kp   = qp   + NTOK;
    float* vp   = kp   + NTOK;
    float* Asum = vp   + NTOK;                    // B*H*NC*64*64 = NTOK
    float* zsum = Asum + NTOK;                    // 32768
    unsigned short* xb   = (unsigned short*)(zsum + 32768);
    unsigned short* Wqkb = xb   + NTOK;           // 1024*512
    unsigned short* Wvb  = Wqkb + 524288;         // 512*512
    unsigned short* Wob  = Wvb  + 262144;         // 512*512
    unsigned short* ctxb = Wob  + 262144;         // NTOK bf16

    convert_bf16 <<<dim3(3072),   256, 0, stream>>>(x, Wqk, Wv, Wo, xb, Wqkb, Wvb, Wob);
    gemm_qkv_mfma<<<dim3(12, 32), 256, 0, stream>>>(xb, Wqkb, Wvb, bqk, bv, qp, kp, vp);
    chunk_sums   <<<dim3(512),    256, 0, stream>>>(kp, vp, Asum, zsum);
    scan_states  <<<dim3(260),    256, 0, stream>>>(Asum, zsum);
    attn_chunk   <<<dim3(512),    256, 0, stream>>>(qp, kp, vp, Asum, zsum, ctxb);
    gemm_out_mfma<<<dim3(4, 64),  256, 0, stream>>>(ctxb, Wob, bo, out);
}

// Round 3
// 130.129 us; speedup vs baseline: 2.0040x; 1.0920x over previous
//
#include <hip/hip_runtime.h>
#include <math.h>

// Problem constants
#define B_N 2
#define S_N 2048
#define DM  512
#define H_N 8
#define DH  64
#define NC  32     // number of chunks = S/64
#define CH  64     // chunk length

typedef __bf16 bf16x8 __attribute__((ext_vector_type(8)));
typedef float  f32x4  __attribute__((ext_vector_type(4)));

__device__ __forceinline__ unsigned short f2bf(float f) {
    unsigned int u = __float_as_uint(f);
    u += 0x7FFFu + ((u >> 16) & 1u);          // round-to-nearest-even
    return (unsigned short)(u >> 16);
}
__device__ __forceinline__ float bf2f(unsigned short u) {
    return __uint_as_float((unsigned int)u << 16);
}

__device__ __forceinline__ void gload16(const void* g, void* l) {
    __builtin_amdgcn_global_load_lds(
        (const __attribute__((address_space(1))) unsigned int*)g,
        (__attribute__((address_space(3))) unsigned int*)l, 16, 0, 0);
}

// ---------------------------------------------------------------------------
// Kernel 0: fp32 -> bf16 conversion of x, Wqk, Wv, Wo.
// ---------------------------------------------------------------------------
__global__ __launch_bounds__(256) void convert_bf16(
    const float* __restrict__ x,  const float* __restrict__ wqk,
    const float* __restrict__ wv, const float* __restrict__ wo,
    unsigned short* __restrict__ xb,  unsigned short* __restrict__ wqkb,
    unsigned short* __restrict__ wvb, unsigned short* __restrict__ wob)
{
    int gid = blockIdx.x * 256 + threadIdx.x;   // 0..786431 float4 units
    const float* src; unsigned short* dst; int off;
    if (gid < 524288)      { src = x;   dst = xb;   off = gid; }
    else if (gid < 655360) { src = wqk; dst = wqkb; off = gid - 524288; }
    else if (gid < 720896) { src = wv;  dst = wvb;  off = gid - 655360; }
    else                   { src = wo;  dst = wob;  off = gid - 720896; }
    float4 v = ((const float4*)src)[off];
    ushort4 r; r.x = f2bf(v.x); r.y = f2bf(v.y); r.z = f2bf(v.z); r.w = f2bf(v.w);
    ((ushort4*)dst)[off] = r;
}

// ---------------------------------------------------------------------------
// Kernel 1: fused QK+V projection via bf16 MFMA.
// Outputs (all bf16): q,k natural [bh][t][d]; kt,vt transposed [bh][d][t].
// ---------------------------------------------------------------------------
__global__ __launch_bounds__(256) void gemm_qkv_mfma(
    const unsigned short* __restrict__ xb,
    const unsigned short* __restrict__ Wqkb,
    const unsigned short* __restrict__ Wvb,
    const float* __restrict__ bqk, const float* __restrict__ bv,
    unsigned short* __restrict__ qb, unsigned short* __restrict__ kb_,
    unsigned short* __restrict__ ktb, unsigned short* __restrict__ vtb)
{
    __shared__ unsigned short Alds[128 * 32];
    __shared__ unsigned short Blds[128 * 32];
    const int tid = threadIdx.x;
    const int w = tid >> 6, l = tid & 63;
    const int wm = w >> 1, wn = w & 1;
    const int lane15 = l & 15, quad = l >> 4;
    const int n0 = blockIdx.x * 128;   // grid.x = 12
    const int m0 = blockIdx.y * 128;   // grid.y = 32

    const unsigned short* Wb; const float* bias; int nc0;
    if (n0 < 1024) { Wb = Wqkb; bias = bqk; nc0 = n0;        }
    else           { Wb = Wvb;  bias = bv;  nc0 = n0 - 1024; }

    const int srow = w * 16 + (l >> 2);
    const int skof = (l & 3) << 3;

    f32x4 acc[4][4];
    #pragma unroll
    for (int i = 0; i < 4; i++)
        #pragma unroll
        for (int j = 0; j < 4; j++) acc[i][j] = (f32x4){0.f, 0.f, 0.f, 0.f};

    for (int k0 = 0; k0 < DM; k0 += 32) {
        __syncthreads();
        gload16(&xb[(size_t)(m0 + srow) * DM + k0 + skof],       (char*)Alds + w * 1024);
        gload16(&xb[(size_t)(m0 + 64 + srow) * DM + k0 + skof],  (char*)Alds + 4096 + w * 1024);
        gload16(&Wb[(size_t)(nc0 + srow) * DM + k0 + skof],      (char*)Blds + w * 1024);
        gload16(&Wb[(size_t)(nc0 + 64 + srow) * DM + k0 + skof], (char*)Blds + 4096 + w * 1024);
        __syncthreads();

        bf16x8 af[4], bfr[4];
        #pragma unroll
        for (int i = 0; i < 4; i++) {
            af[i]  = *(bf16x8*)&Alds[(wm * 64 + i * 16 + lane15) * 32 + quad * 8];
            bfr[i] = *(bf16x8*)&Blds[(wn * 64 + i * 16 + lane15) * 32 + quad * 8];
        }
        #pragma unroll
        for (int i = 0; i < 4; i++)
            #pragma unroll
            for (int j = 0; j < 4; j++)
                acc[i][j] = __builtin_amdgcn_mfma_f32_16x16x32_bf16(af[i], bfr[j], acc[i][j], 0, 0, 0);
    }

    #pragma unroll
    for (int i = 0; i < 4; i++) {
        #pragma unroll
        for (int rg = 0; rg < 4; rg++) {
            int m = m0 + wm * 64 + i * 16 + quad * 4 + rg;
            int bb = m >> 11;
            int t  = m & (S_N - 1);
            #pragma unroll
            for (int j = 0; j < 4; j++) {
                int ncol = wn * 64 + j * 16 + lane15;      // 0..127 within tile
                float val = acc[i][j][rg] + bias[nc0 + ncol];
                int n = n0 + ncol;
                if (n < 1024) val = (val > 0.f) ? (val + 1.f) : __expf(val);  // elu+1
                unsigned short us = f2bf(val);
                if (n < 512) {
                    int h = n >> 6, d = n & 63;
                    qb[(((size_t)bb * H_N + h) * S_N + t) * DH + d] = us;
                } else if (n < 1024) {
                    int nn = n - 512, h = nn >> 6, d = nn & 63;
                    kb_[(((size_t)bb * H_N + h) * S_N + t) * DH + d] = us;
                    ktb[(((size_t)bb * H_N + h) * DH + d) * S_N + t] = us;
                } else {
                    int nn = n - 1024, h = nn >> 6, d = nn & 63;
                    vtb[(((size_t)bb * H_N + h) * DH + d) * S_N + t] = us;
                }
            }
        }
    }
}

// ---------------------------------------------------------------------------
// Kernel 2: per-chunk state sums via MFMA.
//   St[d2][d1] = sum_t vt[d2][t] * kt[d1][t]   (state stored TRANSPOSED)
//   z[d1]      = sum_t k[t][d1]
// One block per (bh,chunk); wave w computes St rows d2 = 16w..16w+15.
// Fragments loaded directly from global (contiguous-K granules).
// ---------------------------------------------------------------------------
__global__ __launch_bounds__(256) void chunk_sums_mfma(
    const unsigned short* __restrict__ ktb, const unsigned short* __restrict__ vtb,
    float* __restrict__ Asum, float* __restrict__ zsum)
{
    __shared__ float zpart[64][4];
    const int blk = blockIdx.x;           // 0..511
    const int bh = blk >> 5, c = blk & 31;
    const unsigned short* ktc = ktb + (size_t)bh * DH * S_N + c * CH;
    const unsigned short* vtc = vtb + (size_t)bh * DH * S_N + c * CH;
    const int tid = threadIdx.x;
    const int w = tid >> 6, l = tid & 63;
    const int lane15 = l & 15, quad = l >> 4;

    bf16x8 va[2];
    #pragma unroll
    for (int s = 0; s < 2; s++)
        va[s] = *(const bf16x8*)&vtc[(size_t)(w * 16 + lane15) * S_N + s * 32 + quad * 8];

    f32x4 acc[4];
    #pragma unroll
    for (int j = 0; j < 4; j++) acc[j] = (f32x4){0.f, 0.f, 0.f, 0.f};
    #pragma unroll
    for (int j = 0; j < 4; j++)
        #pragma unroll
        for (int s = 0; s < 2; s++) {
            bf16x8 kb = *(const bf16x8*)&ktc[(size_t)(j * 16 + lane15) * S_N + s * 32 + quad * 8];
            acc[j] = __builtin_amdgcn_mfma_f32_16x16x32_bf16(va[s], kb, acc[j], 0, 0, 0);
        }

    #pragma unroll
    for (int j = 0; j < 4; j++)
        #pragma unroll
        for (int rg = 0; rg < 4; rg++)
            Asum[(size_t)blk * 4096 + (w * 16 + quad * 4 + rg) * 64 + j * 16 + lane15] = acc[j][rg];

    // z[d1] = row-sum of kt rows (contiguous 64 bf16)
    const int d1 = tid >> 2, part = tid & 3;
    bf16x8 k0 = *(const bf16x8*)&ktc[(size_t)d1 * S_N + part * 16];
    bf16x8 k1 = *(const bf16x8*)&ktc[(size_t)d1 * S_N + part * 16 + 8];
    float zp = 0.f;
    #pragma unroll
    for (int i = 0; i < 8; i++) zp += (float)k0[i] + (float)k1[i];
    zpart[d1][part] = zp;
    __syncthreads();
    if (tid < 64)
        zsum[(size_t)blk * 64 + tid] = zpart[tid][0] + zpart[tid][1] + zpart[tid][2] + zpart[tid][3];
}

// ---------------------------------------------------------------------------
// Kernel 3: exclusive prefix scan over chunks.  States -> bf16, z in-place fp32.
// ---------------------------------------------------------------------------
__global__ __launch_bounds__(256) void scan_states(
    const float* __restrict__ Asum, float* __restrict__ zsum,
    unsigned short* __restrict__ Sptb)
{
    const int gid = blockIdx.x * 256 + threadIdx.x;   // 0..66559
    const int bh = gid / 4160;
    const int r  = gid % 4160;
    if (r < 4096) {
        size_t base = (size_t)bh * NC * 4096 + r;
        float acc = 0.f;
        for (int c = 0; c < NC; c++) {
            float tmp = Asum[base + (size_t)c * 4096];
            Sptb[base + (size_t)c * 4096] = f2bf(acc);
            acc += tmp;
        }
    } else {
        int d = r - 4096;
        size_t base = (size_t)bh * NC * 64 + d;
        float acc = 0.f;
        for (int c = 0; c < NC; c++) {
            float tmp = zsum[base + (size_t)c * 64];
            zsum[base + (size_t)c * 64] = acc;
            acc += tmp;
        }
    }
}

// ---------------------------------------------------------------------------
// Kernel 4: per-chunk attention, all-MFMA.
//   S = q k^T (MFMA, causal mask) -> P bf16 via LDS
//   nu[t] = rowsum(P) + q_t . zprev
//   num   = MFMA(P, vt) + MFMA(q, Spt)   (one accumulator)
//   ctx   = num / nu  -> bf16 [m][DM]
// Wave w owns rows 16w..16w+15; P/nu traffic is wave-local.
// ---------------------------------------------------------------------------
__global__ __launch_bounds__(256) void attn_mfma(
    const unsigned short* __restrict__ qb, const unsigned short* __restrict__ kb_,
    const unsigned short* __restrict__ vtb, const unsigned short* __restrict__ Sptb,
    const float* __restrict__ zsum, unsigned short* __restrict__ ctxb)
{
    __shared__ __align__(16) unsigned short P[64 * 72];
    __shared__ float nupart[64][4];

    const int blk = blockIdx.x;           // 0..511
    const int bh = blk >> 5, c = blk & 31;
    const int b = bh >> 3, h = bh & 7;
    const int tid = threadIdx.x;
    const int w = tid >> 6, l = tid & 63;
    const int lane15 = l & 15, quad = l >> 4;

    const unsigned short* qc  = qb  + (size_t)bh * S_N * DH + c * CH * DH;  // [t][d]
    const unsigned short* kc  = kb_ + (size_t)bh * S_N * DH + c * CH * DH;  // [u][d]
    const unsigned short* vtc = vtb + (size_t)bh * DH * S_N + c * CH;       // [d2][t], stride S_N
    const unsigned short* spc = Sptb + (size_t)blk * 4096;                  // [d2][d1]
    const float* zc = zsum + (size_t)blk * 64;

    // A fragments: q rows 16w..16w+15 (reused for scores and inter)
    bf16x8 af[2];
    #pragma unroll
    for (int s = 0; s < 2; s++)
        af[s] = *(const bf16x8*)&qc[(w * 16 + lane15) * DH + s * 32 + quad * 8];

    // scores S[t][u]
    f32x4 sacc[4];
    #pragma unroll
    for (int j = 0; j < 4; j++) sacc[j] = (f32x4){0.f, 0.f, 0.f, 0.f};
    #pragma unroll
    for (int j = 0; j < 4; j++)
        #pragma unroll
        for (int s = 0; s < 2; s++) {
            bf16x8 bk = *(const bf16x8*)&kc[(j * 16 + lane15) * DH + s * 32 + quad * 8];
            sacc[j] = __builtin_amdgcn_mfma_f32_16x16x32_bf16(af[s], bk, sacc[j], 0, 0, 0);
        }

    // causal mask + store P (bf16) to LDS
    const int r0 = w * 16 + quad * 4;
    #pragma unroll
    for (int j = 0; j < 4; j++) {
        int u = j * 16 + lane15;
        #pragma unroll
        for (int rg = 0; rg < 4; rg++) {
            int rr = r0 + rg;
            float v = (u <= rr) ? sacc[j][rg] : 0.f;
            P[rr * 72 + u] = f2bf(v);
        }
    }
    __syncthreads();

    // nu: thread (tl, part) sums P[tl][16*part..+15] + q.zprev strip
    const int tl = tid >> 2, part = tid & 3;
    float nup = 0.f;
    {
        bf16x8 p0 = *(const bf16x8*)&P[tl * 72 + part * 16];
        bf16x8 p1 = *(const bf16x8*)&P[tl * 72 + part * 16 + 8];
        bf16x8 q0 = *(const bf16x8*)&qc[tl * DH + part * 16];
        bf16x8 q1 = *(const bf16x8*)&qc[tl * DH + part * 16 + 8];
        #pragma unroll
        for (int i = 0; i < 8; i++) {
            nup += (float)p0[i] + (float)p1[i];
            nup += (float)q0[i] * zc[part * 16 + i];
            nup += (float)q1[i] * zc[part * 16 + 8 + i];
        }
    }
    nupart[tl][part] = nup;
    __syncthreads();

    // numerator: intra (P @ vt) + inter (q @ Spt), fused accumulator
    bf16x8 pa[2];
    #pragma unroll
    for (int s = 0; s < 2; s++)
        pa[s] = *(const bf16x8*)&P[(w * 16 + lane15) * 72 + s * 32 + quad * 8];

    f32x4 acc[4];
    #pragma unroll
    for (int j = 0; j < 4; j++) acc[j] = (f32x4){0.f, 0.f, 0.f, 0.f};
    #pragma unroll
    for (int j = 0; j < 4; j++)
        #pragma unroll
        for (int s = 0; s < 2; s++) {
            bf16x8 bv = *(const bf16x8*)&vtc[(size_t)(j * 16 + lane15) * S_N + s * 32 + quad * 8];
            acc[j] = __builtin_amdgcn_mfma_f32_16x16x32_bf16(pa[s], bv, acc[j], 0, 0, 0);
            bf16x8 bs = *(const bf16x8*)&spc[(j * 16 + lane15) * 64 + s * 32 + quad * 8];
            acc[j] = __builtin_amdgcn_mfma_f32_16x16x32_bf16(af[s], bs, acc[j], 0, 0, 0);
        }

    // epilogue: divide by nu, write ctx bf16 [b*S+t][DM]
    #pragma unroll
    for (int rg = 0; rg < 4; rg++) {
        int rr = r0 + rg;
        float nu = nupart[rr][0] + nupart[rr][1] + nupart[rr][2] + nupart[rr][3];
        float inv = 1.f / nu;
        size_t obase = ((size_t)b * S_N + c * CH + rr) * DM + h * DH;
        #pragma unroll
        for (int j = 0; j < 4; j++)
            ctxb[obase + j * 16 + lane15] = f2bf(acc[j][rg] * inv);
    }
}

// ---------------------------------------------------------------------------
// Kernel 5: output projection via bf16 MFMA.
// ---------------------------------------------------------------------------
__global__ __launch_bounds__(256) void gemm_out_mfma(
    const unsigned short* __restrict__ ctxb,
    const unsigned short* __restrict__ Wob,
    const float* __restrict__ bo, float* __restrict__ out)
{
    __shared__ unsigned short Alds[64 * 32];
    __shared__ unsigned short Blds[128 * 32];
    const int tid = threadIdx.x;
    const int w = tid >> 6, l = tid & 63;
    const int wm = w >> 1, wn = w & 1;
    const int lane15 = l & 15, quad = l >> 4;
    const int n0 = blockIdx.x * 128;   // grid.x = 4
    const int m0 = blockIdx.y * 64;    // grid.y = 64

    const int srow = w * 16 + (l >> 2);
    const int skof = (l & 3) << 3;

    f32x4 acc[2][4];
    #pragma unroll
    for (int i = 0; i < 2; i++)
        #pragma unroll
        for (int j = 0; j < 4; j++) acc[i][j] = (f32x4){0.f, 0.f, 0.f, 0.f};

    for (int k0 = 0; k0 < DM; k0 += 32) {
        __syncthreads();
        gload16(&ctxb[(size_t)(m0 + srow) * DM + k0 + skof],      (char*)Alds + w * 1024);
        gload16(&Wob[(size_t)(n0 + srow) * DM + k0 + skof],       (char*)Blds + w * 1024);
        gload16(&Wob[(size_t)(n0 + 64 + srow) * DM + k0 + skof],  (char*)Blds + 4096 + w * 1024);
        __syncthreads();

        bf16x8 af[2], bfr[4];
        #pragma unroll
        for (int i = 0; i < 2; i++)
            af[i] = *(bf16x8*)&Alds[(wm * 32 + i * 16 + lane15) * 32 + quad * 8];
        #pragma unroll
        for (int j = 0; j < 4; j++)
            bfr[j] = *(bf16x8*)&Blds[(wn * 64 + j * 16 + lane15) * 32 + quad * 8];
        #pragma unroll
        for (int i = 0; i < 2; i++)
            #pragma unroll
            for (int j = 0; j < 4; j++)
                acc[i][j] = __builtin_amdgcn_mfma_f32_16x16x32_bf16(af[i], bfr[j], acc[i][j], 0, 0, 0);
    }

    #pragma unroll
    for (int i = 0; i < 2; i++) {
        #pragma unroll
        for (int rg = 0; rg < 4; rg++) {
            int m = m0 + wm * 32 + i * 16 + quad * 4 + rg;
            #pragma unroll
            for (int j = 0; j < 4; j++) {
                int n = n0 + wn * 64 + j * 16 + lane15;
                out[(size_t)m * DM + n] = acc[i][j][rg] + bo[n];
            }
        }
    }
}

// ---------------------------------------------------------------------------
extern "C" void kernel_launch(void* const* d_in, const int* in_sizes, int n_in,
                              void* d_out, int out_size, void* d_ws, size_t ws_size,
                              hipStream_t stream)
{
    const float* x   = (const float*)d_in[0];
    const float* Wqk = (const float*)d_in[1];
    const float* bqk = (const float*)d_in[2];
    const float* Wv  = (const float*)d_in[3];
    const float* bv  = (const float*)d_in[4];
    const float* Wo  = (const float*)d_in[5];
    const float* bo  = (const float*)d_in[6];
    float* out = (float*)d_out;

    const size_t NTOK = (size_t)B_N * S_N * DM;   // 2,097,152
    float* Asum = (float*)d_ws;                   // NTOK fp32
    float* zsum = Asum + NTOK;                    // 32768 fp32
    unsigned short* xb   = (unsigned short*)(zsum + 32768);
    unsigned short* Wqkb = xb   + NTOK;
    unsigned short* Wvb  = Wqkb + 524288;
    unsigned short* Wob  = Wvb  + 262144;
    unsigned short* qb   = Wob  + 262144;
    unsigned short* kb_  = qb   + NTOK;
    unsigned short* ktb  = kb_  + NTOK;
    unsigned short* vtb  = ktb  + NTOK;
    unsigned short* Sptb = vtb  + NTOK;
    unsigned short* ctxb = Sptb + NTOK;

    convert_bf16   <<<dim3(3072),   256, 0, stream>>>(x, Wqk, Wv, Wo, xb, Wqkb, Wvb, Wob);
    gemm_qkv_mfma  <<<dim3(12, 32), 256, 0, stream>>>(xb, Wqkb, Wvb, bqk, bv, qb, kb_, ktb, vtb);
    chunk_sums_mfma<<<dim3(512),    256, 0, stream>>>(ktb, vtb, Asum, zsum);
    scan_states    <<<dim3(260),    256, 0, stream>>>(Asum, zsum, Sptb);
    attn_mfma      <<<dim3(512),    256, 0, stream>>>(qb, kb_, vtb, Sptb, zsum, ctxb);
    gemm_out_mfma  <<<dim3(4, 64),  256, 0, stream>>>(ctxb, Wob, bo, out);
}

// Round 4
// 123.459 us; speedup vs baseline: 2.1122x; 1.0540x over previous
//
#include <hip/hip_runtime.h>
#include <math.h>

// Problem constants
#define B_N 2
#define S_N 2048
#define DM  512
#define H_N 8
#define DH  64
#define NC  32     // number of chunks = S/64
#define CH  64     // chunk length

typedef __bf16 bf16x8 __attribute__((ext_vector_type(8)));
typedef float  f32x4  __attribute__((ext_vector_type(4)));

__device__ __forceinline__ unsigned short f2bf(float f) {
    unsigned int u = __float_as_uint(f);
    u += 0x7FFFu + ((u >> 16) & 1u);          // round-to-nearest-even
    return (unsigned short)(u >> 16);
}

__device__ __forceinline__ void gload16(const void* g, void* l) {
    __builtin_amdgcn_global_load_lds(
        (const __attribute__((address_space(1))) unsigned int*)g,
        (__attribute__((address_space(3))) unsigned int*)l, 16, 0, 0);
}

// ---------------------------------------------------------------------------
// Kernel 0: fp32 -> bf16 conversion of x, Wqk, Wv, Wo.
// ---------------------------------------------------------------------------
__global__ __launch_bounds__(256) void convert_bf16(
    const float* __restrict__ x,  const float* __restrict__ wqk,
    const float* __restrict__ wv, const float* __restrict__ wo,
    unsigned short* __restrict__ xb,  unsigned short* __restrict__ wqkb,
    unsigned short* __restrict__ wvb, unsigned short* __restrict__ wob)
{
    int gid = blockIdx.x * 256 + threadIdx.x;   // 0..786431 float4 units
    const float* src; unsigned short* dst; int off;
    if (gid < 524288)      { src = x;   dst = xb;   off = gid; }
    else if (gid < 655360) { src = wqk; dst = wqkb; off = gid - 524288; }
    else if (gid < 720896) { src = wv;  dst = wvb;  off = gid - 655360; }
    else                   { src = wo;  dst = wob;  off = gid - 720896; }
    float4 v = ((const float4*)src)[off];
    ushort4 r; r.x = f2bf(v.x); r.y = f2bf(v.y); r.z = f2bf(v.z); r.w = f2bf(v.w);
    ((ushort4*)dst)[off] = r;
}

// ---------------------------------------------------------------------------
// Kernel 1: fused projection + per-chunk state sums.
// grid.x = 12:  bx<4  -> q-blocks  (cols bx*128 of Wqk, elu+1, write qb)
//               bx>=4 -> kv-blocks (head h=bx-4: k-cols 512+64h, v-cols 64h)
// kv-block epilogue: k,v -> transposed LDS tiles; then
//   - coalesced copy vT -> vtb global
//   - St[d2][d1] = sum_t v[t][d2] k[t][d1] per chunk via MFMA -> Asum
//   - z[d1] = sum_t k[t][d1] per chunk -> zsum
// m-tile = 128 rows = exactly 2 chunks of one batch.
// ---------------------------------------------------------------------------
__global__ __launch_bounds__(256) void gemm_qkv_fused(
    const unsigned short* __restrict__ xb,
    const unsigned short* __restrict__ Wqkb,
    const unsigned short* __restrict__ Wvb,
    const float* __restrict__ bqk, const float* __restrict__ bv,
    unsigned short* __restrict__ qb, unsigned short* __restrict__ kb_,
    unsigned short* __restrict__ vtb,
    float* __restrict__ Asum, float* __restrict__ zsum)
{
    __shared__ unsigned short Alds[128 * 32];
    __shared__ unsigned short Blds[128 * 32];
    __shared__ unsigned short ktT[64 * 136];   // [d1][t_local], stride 136 (2-way banks, 16B-aligned)
    __shared__ unsigned short vtT[64 * 136];   // [d2][t_local]

    const int tid = threadIdx.x;
    const int w = tid >> 6, l = tid & 63;
    const int wm = w >> 1, wn = w & 1;
    const int lane15 = l & 15, quad = l >> 4;
    const int bx = blockIdx.x;
    const int m0 = blockIdx.y * 128;   // grid.y = 32
    const int isq = (bx < 4);
    const int h = isq ? 0 : (bx - 4);

    const int srow = w * 16 + (l >> 2);
    const int skof = (l & 3) << 3;

    f32x4 acc[4][4];
    #pragma unroll
    for (int i = 0; i < 4; i++)
        #pragma unroll
        for (int j = 0; j < 4; j++) acc[i][j] = (f32x4){0.f, 0.f, 0.f, 0.f};

    for (int k0 = 0; k0 < DM; k0 += 32) {
        __syncthreads();
        gload16(&xb[(size_t)(m0 + srow) * DM + k0 + skof],      (char*)Alds + w * 1024);
        gload16(&xb[(size_t)(m0 + 64 + srow) * DM + k0 + skof], (char*)Alds + 4096 + w * 1024);
        if (isq) {
            gload16(&Wqkb[(size_t)(bx * 128 + srow) * DM + k0 + skof],      (char*)Blds + w * 1024);
            gload16(&Wqkb[(size_t)(bx * 128 + 64 + srow) * DM + k0 + skof], (char*)Blds + 4096 + w * 1024);
        } else {
            gload16(&Wqkb[(size_t)(512 + h * 64 + srow) * DM + k0 + skof],  (char*)Blds + w * 1024);
            gload16(&Wvb[(size_t)(h * 64 + srow) * DM + k0 + skof],         (char*)Blds + 4096 + w * 1024);
        }
        __syncthreads();

        bf16x8 af[4], bfr[4];
        #pragma unroll
        for (int i = 0; i < 4; i++) {
            af[i]  = *(bf16x8*)&Alds[(wm * 64 + i * 16 + lane15) * 32 + quad * 8];
            bfr[i] = *(bf16x8*)&Blds[(wn * 64 + i * 16 + lane15) * 32 + quad * 8];
        }
        #pragma unroll
        for (int i = 0; i < 4; i++)
            #pragma unroll
            for (int j = 0; j < 4; j++)
                acc[i][j] = __builtin_amdgcn_mfma_f32_16x16x32_bf16(af[i], bfr[j], acc[i][j], 0, 0, 0);
    }

    const int bbu = m0 >> 11;          // batch index (block-uniform)
    const int t0  = m0 & (S_N - 1);    // global t of local row 0
    const int c0  = t0 >> 6;           // first chunk index

    if (isq) {
        // ---- q epilogue: bias + elu+1, write qb [bh][t][d] ----
        #pragma unroll
        for (int i = 0; i < 4; i++) {
            #pragma unroll
            for (int rg = 0; rg < 4; rg++) {
                int m = m0 + wm * 64 + i * 16 + quad * 4 + rg;
                int bb = m >> 11, t = m & (S_N - 1);
                #pragma unroll
                for (int j = 0; j < 4; j++) {
                    int n = bx * 128 + wn * 64 + j * 16 + lane15;   // 0..511
                    float val = acc[i][j][rg] + bqk[n];
                    val = (val > 0.f) ? (val + 1.f) : __expf(val);
                    qb[(((size_t)bb * H_N + (n >> 6)) * S_N + t) * DH + (n & 63)] = f2bf(val);
                }
            }
        }
        return;
    }

    // ---- kv epilogue: wn==0 half is k (elu+1), wn==1 half is v ----
    #pragma unroll
    for (int i = 0; i < 4; i++) {
        #pragma unroll
        for (int rg = 0; rg < 4; rg++) {
            int tl = wm * 64 + i * 16 + quad * 4 + rg;   // local row 0..127
            int t  = t0 + tl;
            #pragma unroll
            for (int j = 0; j < 4; j++) {
                int col = j * 16 + lane15;               // 0..63 within half
                if (wn == 0) {
                    float val = acc[i][j][rg] + bqk[512 + h * 64 + col];
                    val = (val > 0.f) ? (val + 1.f) : __expf(val);
                    unsigned short us = f2bf(val);
                    kb_[(((size_t)bbu * H_N + h) * S_N + t) * DH + col] = us;
                    ktT[col * 136 + tl] = us;
                } else {
                    float val = acc[i][j][rg] + bv[h * 64 + col];
                    vtT[col * 136 + tl] = f2bf(val);
                }
            }
        }
    }
    __syncthreads();

    // ---- coalesced copy vT -> vtb global [bh][d][t] ----
    {
        size_t vbase = (((size_t)bbu * H_N + h) * DH) * S_N + t0;
        #pragma unroll
        for (int it = 0; it < 4; it++) {
            int idx = it * 2048 + tid * 8;
            int d = idx >> 7, tt = idx & 127;
            *(bf16x8*)&vtb[vbase + (size_t)d * S_N + tt] = *(bf16x8*)&vtT[d * 136 + tt];
        }
    }

    // ---- St per chunk via MFMA; wave w owns d2 rows 16w..16w+15 ----
    #pragma unroll
    for (int cc = 0; cc < 2; cc++) {
        int blk = ((bbu * H_N + h) * NC) + c0 + cc;
        bf16x8 va[2];
        #pragma unroll
        for (int s = 0; s < 2; s++)
            va[s] = *(bf16x8*)&vtT[(w * 16 + lane15) * 136 + cc * 64 + s * 32 + quad * 8];
        f32x4 sacc[4];
        #pragma unroll
        for (int j = 0; j < 4; j++) sacc[j] = (f32x4){0.f, 0.f, 0.f, 0.f};
        #pragma unroll
        for (int j = 0; j < 4; j++)
            #pragma unroll
            for (int s = 0; s < 2; s++) {
                bf16x8 kB = *(bf16x8*)&ktT[(j * 16 + lane15) * 136 + cc * 64 + s * 32 + quad * 8];
                sacc[j] = __builtin_amdgcn_mfma_f32_16x16x32_bf16(va[s], kB, sacc[j], 0, 0, 0);
            }
        #pragma unroll
        for (int j = 0; j < 4; j++)
            #pragma unroll
            for (int rg = 0; rg < 4; rg++)
                Asum[(size_t)blk * 4096 + (w * 16 + quad * 4 + rg) * 64 + j * 16 + lane15] = sacc[j][rg];
    }

    // ---- z per chunk: threads 0..127, one (cc, d1) each ----
    if (tid < 128) {
        int cc = tid >> 6, d1 = tid & 63;
        float z = 0.f;
        #pragma unroll
        for (int p = 0; p < 8; p++) {
            bf16x8 kk = *(bf16x8*)&ktT[d1 * 136 + cc * 64 + p * 8];
            #pragma unroll
            for (int e = 0; e < 8; e++) z += (float)kk[e];
        }
        zsum[(size_t)((bbu * H_N + h) * NC + c0 + cc) * 64 + d1] = z;
    }
}

// ---------------------------------------------------------------------------
// Kernel 3: exclusive prefix scan over chunks.  States -> bf16, z in-place fp32.
// ---------------------------------------------------------------------------
__global__ __launch_bounds__(256) void scan_states(
    const float* __restrict__ Asum, float* __restrict__ zsum,
    unsigned short* __restrict__ Sptb)
{
    const int gid = blockIdx.x * 256 + threadIdx.x;   // 0..66559
    const int bh = gid / 4160;
    const int r  = gid % 4160;
    if (r < 4096) {
        size_t base = (size_t)bh * NC * 4096 + r;
        float acc = 0.f;
        for (int c = 0; c < NC; c++) {
            float tmp = Asum[base + (size_t)c * 4096];
            Sptb[base + (size_t)c * 4096] = f2bf(acc);
            acc += tmp;
        }
    } else {
        int d = r - 4096;
        size_t base = (size_t)bh * NC * 64 + d;
        float acc = 0.f;
        for (int c = 0; c < NC; c++) {
            float tmp = zsum[base + (size_t)c * 64];
            zsum[base + (size_t)c * 64] = acc;
            acc += tmp;
        }
    }
}

// ---------------------------------------------------------------------------
// Kernel 4: per-chunk attention, all-MFMA.
// ---------------------------------------------------------------------------
__global__ __launch_bounds__(256) void attn_mfma(
    const unsigned short* __restrict__ qb, const unsigned short* __restrict__ kb_,
    const unsigned short* __restrict__ vtb, const unsigned short* __restrict__ Sptb,
    const float* __restrict__ zsum, unsigned short* __restrict__ ctxb)
{
    __shared__ __align__(16) unsigned short P[64 * 72];
    __shared__ float nupart[64][4];

    const int blk = blockIdx.x;           // 0..511
    const int bh = blk >> 5, c = blk & 31;
    const int b = bh >> 3, h = bh & 7;
    const int tid = threadIdx.x;
    const int w = tid >> 6, l = tid & 63;
    const int lane15 = l & 15, quad = l >> 4;

    const unsigned short* qc  = qb  + (size_t)bh * S_N * DH + c * CH * DH;  // [t][d]
    const unsigned short* kc  = kb_ + (size_t)bh * S_N * DH + c * CH * DH;  // [u][d]
    const unsigned short* vtc = vtb + (size_t)bh * DH * S_N + c * CH;       // [d2][t], stride S_N
    const unsigned short* spc = Sptb + (size_t)blk * 4096;                  // [d2][d1]
    const float* zc = zsum + (size_t)blk * 64;

    bf16x8 af[2];
    #pragma unroll
    for (int s = 0; s < 2; s++)
        af[s] = *(const bf16x8*)&qc[(w * 16 + lane15) * DH + s * 32 + quad * 8];

    // scores S[t][u]
    f32x4 sacc[4];
    #pragma unroll
    for (int j = 0; j < 4; j++) sacc[j] = (f32x4){0.f, 0.f, 0.f, 0.f};
    #pragma unroll
    for (int j = 0; j < 4; j++)
        #pragma unroll
        for (int s = 0; s < 2; s++) {
            bf16x8 bk = *(const bf16x8*)&kc[(j * 16 + lane15) * DH + s * 32 + quad * 8];
            sacc[j] = __builtin_amdgcn_mfma_f32_16x16x32_bf16(af[s], bk, sacc[j], 0, 0, 0);
        }

    // causal mask + store P (bf16) to LDS
    const int r0 = w * 16 + quad * 4;
    #pragma unroll
    for (int j = 0; j < 4; j++) {
        int u = j * 16 + lane15;
        #pragma unroll
        for (int rg = 0; rg < 4; rg++) {
            int rr = r0 + rg;
            float v = (u <= rr) ? sacc[j][rg] : 0.f;
            P[rr * 72 + u] = f2bf(v);
        }
    }
    __syncthreads();

    // nu: thread (tl, part) sums P[tl][16*part..+15] + q.zprev strip
    const int tl = tid >> 2, part = tid & 3;
    float nup = 0.f;
    {
        bf16x8 p0 = *(const bf16x8*)&P[tl * 72 + part * 16];
        bf16x8 p1 = *(const bf16x8*)&P[tl * 72 + part * 16 + 8];
        bf16x8 q0 = *(const bf16x8*)&qc[tl * DH + part * 16];
        bf16x8 q1 = *(const bf16x8*)&qc[tl * DH + part * 16 + 8];
        #pragma unroll
        for (int i = 0; i < 8; i++) {
            nup += (float)p0[i] + (float)p1[i];
            nup += (float)q0[i] * zc[part * 16 + i];
            nup += (float)q1[i] * zc[part * 16 + 8 + i];
        }
    }
    nupart[tl][part] = nup;
    __syncthreads();

    // numerator: intra (P @ vt) + inter (q @ Spt), fused accumulator
    bf16x8 pa[2];
    #pragma unroll
    for (int s = 0; s < 2; s++)
        pa[s] = *(const bf16x8*)&P[(w * 16 + lane15) * 72 + s * 32 + quad * 8];

    f32x4 acc[4];
    #pragma unroll
    for (int j = 0; j < 4; j++) acc[j] = (f32x4){0.f, 0.f, 0.f, 0.f};
    #pragma unroll
    for (int j = 0; j < 4; j++)
        #pragma unroll
        for (int s = 0; s < 2; s++) {
            bf16x8 bv = *(const bf16x8*)&vtc[(size_t)(j * 16 + lane15) * S_N + s * 32 + quad * 8];
            acc[j] = __builtin_amdgcn_mfma_f32_16x16x32_bf16(pa[s], bv, acc[j], 0, 0, 0);
            bf16x8 bs = *(const bf16x8*)&spc[(j * 16 + lane15) * 64 + s * 32 + quad * 8];
            acc[j] = __builtin_amdgcn_mfma_f32_16x16x32_bf16(af[s], bs, acc[j], 0, 0, 0);
        }

    // epilogue: divide by nu, write ctx bf16 [b*S+t][DM]
    #pragma unroll
    for (int rg = 0; rg < 4; rg++) {
        int rr = r0 + rg;
        float nu = nupart[rr][0] + nupart[rr][1] + nupart[rr][2] + nupart[rr][3];
        float inv = 1.f / nu;
        size_t obase = ((size_t)b * S_N + c * CH + rr) * DM + h * DH;
        #pragma unroll
        for (int j = 0; j < 4; j++)
            ctxb[obase + j * 16 + lane15] = f2bf(acc[j][rg] * inv);
    }
}

// ---------------------------------------------------------------------------
// Kernel 5: output projection via bf16 MFMA.
// ---------------------------------------------------------------------------
__global__ __launch_bounds__(256) void gemm_out_mfma(
    const unsigned short* __restrict__ ctxb,
    const unsigned short* __restrict__ Wob,
    const float* __restrict__ bo, float* __restrict__ out)
{
    __shared__ unsigned short Alds[64 * 32];
    __shared__ unsigned short Blds[128 * 32];
    const int tid = threadIdx.x;
    const int w = tid >> 6, l = tid & 63;
    const int wm = w >> 1, wn = w & 1;
    const int lane15 = l & 15, quad = l >> 4;
    const int n0 = blockIdx.x * 128;   // grid.x = 4
    const int m0 = blockIdx.y * 64;    // grid.y = 64

    const int srow = w * 16 + (l >> 2);
    const int skof = (l & 3) << 3;

    f32x4 acc[2][4];
    #pragma unroll
    for (int i = 0; i < 2; i++)
        #pragma unroll
        for (int j = 0; j < 4; j++) acc[i][j] = (f32x4){0.f, 0.f, 0.f, 0.f};

    for (int k0 = 0; k0 < DM; k0 += 32) {
        __syncthreads();
        gload16(&ctxb[(size_t)(m0 + srow) * DM + k0 + skof],      (char*)Alds + w * 1024);
        gload16(&Wob[(size_t)(n0 + srow) * DM + k0 + skof],       (char*)Blds + w * 1024);
        gload16(&Wob[(size_t)(n0 + 64 + srow) * DM + k0 + skof],  (char*)Blds + 4096 + w * 1024);
        __syncthreads();

        bf16x8 af[2], bfr[4];
        #pragma unroll
        for (int i = 0; i < 2; i++)
            af[i] = *(bf16x8*)&Alds[(wm * 32 + i * 16 + lane15) * 32 + quad * 8];
        #pragma unroll
        for (int j = 0; j < 4; j++)
            bfr[j] = *(bf16x8*)&Blds[(wn * 64 + j * 16 + lane15) * 32 + quad * 8];
        #pragma unroll
        for (int i = 0; i < 2; i++)
            #pragma unroll
            for (int j = 0; j < 4; j++)
                acc[i][j] = __builtin_amdgcn_mfma_f32_16x16x32_bf16(af[i], bfr[j], acc[i][j], 0, 0, 0);
    }

    #pragma unroll
    for (int i = 0; i < 2; i++) {
        #pragma unroll
        for (int rg = 0; rg < 4; rg++) {
            int m = m0 + wm * 32 + i * 16 + quad * 4 + rg;
            #pragma unroll
            for (int j = 0; j < 4; j++) {
                int n = n0 + wn * 64 + j * 16 + lane15;
                out[(size_t)m * DM + n] = acc[i][j][rg] + bo[n];
            }
        }
    }
}

// ---------------------------------------------------------------------------
extern "C" void kernel_launch(void* const* d_in, const int* in_sizes, int n_in,
                              void* d_out, int out_size, void* d_ws, size_t ws_size,
                              hipStream_t stream)
{
    const float* x   = (const float*)d_in[0];
    const float* Wqk = (const float*)d_in[1];
    const float* bqk = (const float*)d_in[2];
    const float* Wv  = (const float*)d_in[3];
    const float* bv  = (const float*)d_in[4];
    const float* Wo  = (const float*)d_in[5];
    const float* bo  = (const float*)d_in[6];
    float* out = (float*)d_out;

    const size_t NTOK = (size_t)B_N * S_N * DM;   // 2,097,152
    float* Asum = (float*)d_ws;                   // NTOK fp32
    float* zsum = Asum + NTOK;                    // 32768 fp32
    unsigned short* xb   = (unsigned short*)(zsum + 32768);
    unsigned short* Wqkb = xb   + NTOK;
    unsigned short* Wvb  = Wqkb + 524288;
    unsigned short* Wob  = Wvb  + 262144;
    unsigned short* qb   = Wob  + 262144;
    unsigned short* kb_  = qb   + NTOK;
    unsigned short* vtb  = kb_  + NTOK;
    unsigned short* Sptb = vtb  + NTOK;
    unsigned short* ctxb = Sptb + NTOK;

    convert_bf16  <<<dim3(3072),   256, 0, stream>>>(x, Wqk, Wv, Wo, xb, Wqkb, Wvb, Wob);
    gemm_qkv_fused<<<dim3(12, 32), 256, 0, stream>>>(xb, Wqkb, Wvb, bqk, bv, qb, kb_, vtb, Asum, zsum);
    scan_states   <<<dim3(260),    256, 0, stream>>>(Asum, zsum, Sptb);
    attn_mfma     <<<dim3(512),    256, 0, stream>>>(qb, kb_, vtb, Sptb, zsum, ctxb);
    gemm_out_mfma <<<dim3(4, 64),  256, 0, stream>>>(ctxb, Wob, bo, out);
}

// Round 5
// 115.189 us; speedup vs baseline: 2.2639x; 1.0718x over previous
//
#include <hip/hip_runtime.h>
#include <math.h>

// Problem constants
#define B_N 2
#define S_N 2048
#define DM  512
#define H_N 8
#define DH  64
#define NC  32     // number of chunks = S/64
#define CH  64     // chunk length

typedef __bf16 bf16x8 __attribute__((ext_vector_type(8)));
typedef float  f32x4  __attribute__((ext_vector_type(4)));

__device__ __forceinline__ unsigned short f2bf(float f) {
    unsigned int u = __float_as_uint(f);
    u += 0x7FFFu + ((u >> 16) & 1u);          // round-to-nearest-even
    return (unsigned short)(u >> 16);
}

__device__ __forceinline__ void gload16(const void* g, void* l) {
    __builtin_amdgcn_global_load_lds(
        (const __attribute__((address_space(1))) unsigned int*)g,
        (__attribute__((address_space(3))) unsigned int*)l, 16, 0, 0);
}

// ---------------------------------------------------------------------------
// Kernel 0: fp32 -> bf16 conversion of x, Wqk, Wv, Wo.
// ---------------------------------------------------------------------------
__global__ __launch_bounds__(256) void convert_bf16(
    const float* __restrict__ x,  const float* __restrict__ wqk,
    const float* __restrict__ wv, const float* __restrict__ wo,
    unsigned short* __restrict__ xb,  unsigned short* __restrict__ wqkb,
    unsigned short* __restrict__ wvb, unsigned short* __restrict__ wob)
{
    int gid = blockIdx.x * 256 + threadIdx.x;   // 0..786431 float4 units
    const float* src; unsigned short* dst; int off;
    if (gid < 524288)      { src = x;   dst = xb;   off = gid; }
    else if (gid < 655360) { src = wqk; dst = wqkb; off = gid - 524288; }
    else if (gid < 720896) { src = wv;  dst = wvb;  off = gid - 655360; }
    else                   { src = wo;  dst = wob;  off = gid - 720896; }
    float4 v = ((const float4*)src)[off];
    ushort4 r; r.x = f2bf(v.x); r.y = f2bf(v.y); r.z = f2bf(v.z); r.w = f2bf(v.w);
    ((ushort4*)dst)[off] = r;
}

// ---------------------------------------------------------------------------
// Kernel 1: fused projection + per-chunk state sums.  64-row m-tiles (1 chunk).
// grid = (12, 64):  bx<4  -> q-blocks  (cols bx*128 of Wqk, elu+1 -> qb)
//                   bx>=4 -> kv-blocks (head h=bx-4: k-cols 512+64h, v-cols 64h)
// kv epilogue: k,v -> transposed LDS; coalesced vT->vtb; St=MFMA(vT,kT)->Asum;
// z rowsums -> zsum.  3 blocks/CU occupancy.
// ---------------------------------------------------------------------------
__global__ __launch_bounds__(256) void gemm_qkv_fused(
    const unsigned short* __restrict__ xb,
    const unsigned short* __restrict__ Wqkb,
    const unsigned short* __restrict__ Wvb,
    const float* __restrict__ bqk, const float* __restrict__ bv,
    unsigned short* __restrict__ qb, unsigned short* __restrict__ kb_,
    unsigned short* __restrict__ vtb,
    float* __restrict__ Asum, float* __restrict__ zsum)
{
    __shared__ unsigned short Alds[64 * 32];
    __shared__ unsigned short Blds[128 * 32];
    __shared__ unsigned short ktT[64 * 72];   // [d1][t_local] stride 72 (16B-aligned rows)
    __shared__ unsigned short vtT[64 * 72];   // [d2][t_local]

    const int tid = threadIdx.x;
    const int w = tid >> 6, l = tid & 63;
    const int wm = w >> 1, wn = w & 1;
    const int lane15 = l & 15, quad = l >> 4;
    const int bx = blockIdx.x;
    const int m0 = blockIdx.y * 64;    // grid.y = 64
    const int isq = (bx < 4);
    const int h = isq ? 0 : (bx - 4);

    const int srow = w * 16 + (l >> 2);   // 0..63
    const int skof = (l & 3) << 3;

    f32x4 acc[2][4];
    #pragma unroll
    for (int i = 0; i < 2; i++)
        #pragma unroll
        for (int j = 0; j < 4; j++) acc[i][j] = (f32x4){0.f, 0.f, 0.f, 0.f};

    for (int k0 = 0; k0 < DM; k0 += 32) {
        __syncthreads();
        gload16(&xb[(size_t)(m0 + srow) * DM + k0 + skof], (char*)Alds + w * 1024);
        if (isq) {
            gload16(&Wqkb[(size_t)(bx * 128 + srow) * DM + k0 + skof],      (char*)Blds + w * 1024);
            gload16(&Wqkb[(size_t)(bx * 128 + 64 + srow) * DM + k0 + skof], (char*)Blds + 4096 + w * 1024);
        } else {
            gload16(&Wqkb[(size_t)(512 + h * 64 + srow) * DM + k0 + skof],  (char*)Blds + w * 1024);
            gload16(&Wvb[(size_t)(h * 64 + srow) * DM + k0 + skof],         (char*)Blds + 4096 + w * 1024);
        }
        __syncthreads();

        bf16x8 af[2], bfr[4];
        #pragma unroll
        for (int i = 0; i < 2; i++)
            af[i] = *(bf16x8*)&Alds[(wm * 32 + i * 16 + lane15) * 32 + quad * 8];
        #pragma unroll
        for (int j = 0; j < 4; j++)
            bfr[j] = *(bf16x8*)&Blds[(wn * 64 + j * 16 + lane15) * 32 + quad * 8];
        #pragma unroll
        for (int i = 0; i < 2; i++)
            #pragma unroll
            for (int j = 0; j < 4; j++)
                acc[i][j] = __builtin_amdgcn_mfma_f32_16x16x32_bf16(af[i], bfr[j], acc[i][j], 0, 0, 0);
    }

    const int bbu = m0 >> 11;          // batch index (block-uniform)
    const int t0  = m0 & (S_N - 1);    // global t of local row 0
    const int c0  = t0 >> 6;           // chunk index

    if (isq) {
        #pragma unroll
        for (int i = 0; i < 2; i++) {
            #pragma unroll
            for (int rg = 0; rg < 4; rg++) {
                int m = m0 + wm * 32 + i * 16 + quad * 4 + rg;
                int bb = m >> 11, t = m & (S_N - 1);
                #pragma unroll
                for (int j = 0; j < 4; j++) {
                    int n = bx * 128 + wn * 64 + j * 16 + lane15;   // 0..511
                    float val = acc[i][j][rg] + bqk[n];
                    val = (val > 0.f) ? (val + 1.f) : __expf(val);
                    qb[(((size_t)bb * H_N + (n >> 6)) * S_N + t) * DH + (n & 63)] = f2bf(val);
                }
            }
        }
        return;
    }

    // ---- kv epilogue: wn==0 half is k (elu+1), wn==1 half is v ----
    #pragma unroll
    for (int i = 0; i < 2; i++) {
        #pragma unroll
        for (int rg = 0; rg < 4; rg++) {
            int tl = wm * 32 + i * 16 + quad * 4 + rg;   // local row 0..63
            int t  = t0 + tl;
            #pragma unroll
            for (int j = 0; j < 4; j++) {
                int col = j * 16 + lane15;               // 0..63 within half
                if (wn == 0) {
                    float val = acc[i][j][rg] + bqk[512 + h * 64 + col];
                    val = (val > 0.f) ? (val + 1.f) : __expf(val);
                    unsigned short us = f2bf(val);
                    kb_[(((size_t)bbu * H_N + h) * S_N + t) * DH + col] = us;
                    ktT[col * 72 + tl] = us;
                } else {
                    float val = acc[i][j][rg] + bv[h * 64 + col];
                    vtT[col * 72 + tl] = f2bf(val);
                }
            }
        }
    }
    __syncthreads();

    // ---- coalesced copy vT -> vtb global [bh][d][t] ----
    {
        size_t vbase = (((size_t)bbu * H_N + h) * DH) * S_N + t0;
        #pragma unroll
        for (int it = 0; it < 2; it++) {
            int idx = it * 2048 + tid * 8;
            int d = idx >> 6, tt = idx & 63;
            *(bf16x8*)&vtb[vbase + (size_t)d * S_N + tt] = *(bf16x8*)&vtT[d * 72 + tt];
        }
    }

    // ---- St via MFMA; wave w owns d2 rows 16w..16w+15 ----
    {
        int blk = ((bbu * H_N + h) * NC) + c0;
        bf16x8 va[2];
        #pragma unroll
        for (int s = 0; s < 2; s++)
            va[s] = *(bf16x8*)&vtT[(w * 16 + lane15) * 72 + s * 32 + quad * 8];
        f32x4 sacc[4];
        #pragma unroll
        for (int j = 0; j < 4; j++) sacc[j] = (f32x4){0.f, 0.f, 0.f, 0.f};
        #pragma unroll
        for (int j = 0; j < 4; j++)
            #pragma unroll
            for (int s = 0; s < 2; s++) {
                bf16x8 kB = *(bf16x8*)&ktT[(j * 16 + lane15) * 72 + s * 32 + quad * 8];
                sacc[j] = __builtin_amdgcn_mfma_f32_16x16x32_bf16(va[s], kB, sacc[j], 0, 0, 0);
            }
        #pragma unroll
        for (int j = 0; j < 4; j++)
            #pragma unroll
            for (int rg = 0; rg < 4; rg++)
                Asum[(size_t)blk * 4096 + (w * 16 + quad * 4 + rg) * 64 + j * 16 + lane15] = sacc[j][rg];
    }

    // ---- z: threads 0..63, one d1 each ----
    if (tid < 64) {
        float z = 0.f;
        #pragma unroll
        for (int p = 0; p < 8; p++) {
            bf16x8 kk = *(bf16x8*)&ktT[tid * 72 + p * 8];
            #pragma unroll
            for (int e = 0; e < 8; e++) z += (float)kk[e];
        }
        zsum[(size_t)((bbu * H_N + h) * NC + c0) * 64 + tid] = z;
    }
}

// ---------------------------------------------------------------------------
// Kernel 2: exclusive prefix scan over chunks — register-batched (32 loads in
// flight, prefix in-register, 32 independent stores).  States -> bf16.
// ---------------------------------------------------------------------------
__global__ __launch_bounds__(256) void scan_states(
    const float* __restrict__ Asum, float* __restrict__ zsum,
    unsigned short* __restrict__ Sptb)
{
    const int gid = blockIdx.x * 256 + threadIdx.x;   // 0..66559
    const int bh = gid / 4160;
    const int r  = gid % 4160;
    if (r < 4096) {
        size_t base = (size_t)bh * NC * 4096 + r;
        float vals[NC];
        #pragma unroll
        for (int c = 0; c < NC; c++) vals[c] = Asum[base + (size_t)c * 4096];
        float acc = 0.f;
        #pragma unroll
        for (int c = 0; c < NC; c++) {
            float tmp = vals[c];
            Sptb[base + (size_t)c * 4096] = f2bf(acc);
            acc += tmp;
        }
    } else {
        int d = r - 4096;
        size_t base = (size_t)bh * NC * 64 + d;
        float vals[NC];
        #pragma unroll
        for (int c = 0; c < NC; c++) vals[c] = zsum[base + (size_t)c * 64];
        float acc = 0.f;
        #pragma unroll
        for (int c = 0; c < NC; c++) {
            float tmp = vals[c];
            zsum[base + (size_t)c * 64] = acc;
            acc += tmp;
        }
    }
}

// ---------------------------------------------------------------------------
// Kernel 3: per-chunk attention, all-MFMA.
// ---------------------------------------------------------------------------
__global__ __launch_bounds__(256) void attn_mfma(
    const unsigned short* __restrict__ qb, const unsigned short* __restrict__ kb_,
    const unsigned short* __restrict__ vtb, const unsigned short* __restrict__ Sptb,
    const float* __restrict__ zsum, unsigned short* __restrict__ ctxb)
{
    __shared__ __align__(16) unsigned short P[64 * 72];
    __shared__ float nupart[64][4];

    const int blk = blockIdx.x;           // 0..511
    const int bh = blk >> 5, c = blk & 31;
    const int b = bh >> 3, h = bh & 7;
    const int tid = threadIdx.x;
    const int w = tid >> 6, l = tid & 63;
    const int lane15 = l & 15, quad = l >> 4;

    const unsigned short* qc  = qb  + (size_t)bh * S_N * DH + c * CH * DH;  // [t][d]
    const unsigned short* kc  = kb_ + (size_t)bh * S_N * DH + c * CH * DH;  // [u][d]
    const unsigned short* vtc = vtb + (size_t)bh * DH * S_N + c * CH;       // [d2][t], stride S_N
    const unsigned short* spc = Sptb + (size_t)blk * 4096;                  // [d2][d1]
    const float* zc = zsum + (size_t)blk * 64;

    bf16x8 af[2];
    #pragma unroll
    for (int s = 0; s < 2; s++)
        af[s] = *(const bf16x8*)&qc[(w * 16 + lane15) * DH + s * 32 + quad * 8];

    // scores S[t][u]
    f32x4 sacc[4];
    #pragma unroll
    for (int j = 0; j < 4; j++) sacc[j] = (f32x4){0.f, 0.f, 0.f, 0.f};
    #pragma unroll
    for (int j = 0; j < 4; j++)
        #pragma unroll
        for (int s = 0; s < 2; s++) {
            bf16x8 bk = *(const bf16x8*)&kc[(j * 16 + lane15) * DH + s * 32 + quad * 8];
            sacc[j] = __builtin_amdgcn_mfma_f32_16x16x32_bf16(af[s], bk, sacc[j], 0, 0, 0);
        }

    // causal mask + store P (bf16) to LDS
    const int r0 = w * 16 + quad * 4;
    #pragma unroll
    for (int j = 0; j < 4; j++) {
        int u = j * 16 + lane15;
        #pragma unroll
        for (int rg = 0; rg < 4; rg++) {
            int rr = r0 + rg;
            float v = (u <= rr) ? sacc[j][rg] : 0.f;
            P[rr * 72 + u] = f2bf(v);
        }
    }
    __syncthreads();

    // nu: thread (tl, part) sums P[tl][16*part..+15] + q.zprev strip
    const int tl = tid >> 2, part = tid & 3;
    float nup = 0.f;
    {
        bf16x8 p0 = *(const bf16x8*)&P[tl * 72 + part * 16];
        bf16x8 p1 = *(const bf16x8*)&P[tl * 72 + part * 16 + 8];
        bf16x8 q0 = *(const bf16x8*)&qc[tl * DH + part * 16];
        bf16x8 q1 = *(const bf16x8*)&qc[tl * DH + part * 16 + 8];
        #pragma unroll
        for (int i = 0; i < 8; i++) {
            nup += (float)p0[i] + (float)p1[i];
            nup += (float)q0[i] * zc[part * 16 + i];
            nup += (float)q1[i] * zc[part * 16 + 8 + i];
        }
    }
    nupart[tl][part] = nup;
    __syncthreads();

    // numerator: intra (P @ vt) + inter (q @ Spt), fused accumulator
    bf16x8 pa[2];
    #pragma unroll
    for (int s = 0; s < 2; s++)
        pa[s] = *(const bf16x8*)&P[(w * 16 + lane15) * 72 + s * 32 + quad * 8];

    f32x4 acc[4];
    #pragma unroll
    for (int j = 0; j < 4; j++) acc[j] = (f32x4){0.f, 0.f, 0.f, 0.f};
    #pragma unroll
    for (int j = 0; j < 4; j++)
        #pragma unroll
        for (int s = 0; s < 2; s++) {
            bf16x8 bv = *(const bf16x8*)&vtc[(size_t)(j * 16 + lane15) * S_N + s * 32 + quad * 8];
            acc[j] = __builtin_amdgcn_mfma_f32_16x16x32_bf16(pa[s], bv, acc[j], 0, 0, 0);
            bf16x8 bs = *(const bf16x8*)&spc[(j * 16 + lane15) * 64 + s * 32 + quad * 8];
            acc[j] = __builtin_amdgcn_mfma_f32_16x16x32_bf16(af[s], bs, acc[j], 0, 0, 0);
        }

    // epilogue: divide by nu, write ctx bf16 [b*S+t][DM]
    #pragma unroll
    for (int rg = 0; rg < 4; rg++) {
        int rr = r0 + rg;
        float nu = nupart[rr][0] + nupart[rr][1] + nupart[rr][2] + nupart[rr][3];
        float inv = 1.f / nu;
        size_t obase = ((size_t)b * S_N + c * CH + rr) * DM + h * DH;
        #pragma unroll
        for (int j = 0; j < 4; j++)
            ctxb[obase + j * 16 + lane15] = f2bf(acc[j][rg] * inv);
    }
}

// ---------------------------------------------------------------------------
// Kernel 4: output projection via bf16 MFMA.  64x64 tiles, grid (8,64).
// ---------------------------------------------------------------------------
__global__ __launch_bounds__(256) void gemm_out_mfma(
    const unsigned short* __restrict__ ctxb,
    const unsigned short* __restrict__ Wob,
    const float* __restrict__ bo, float* __restrict__ out)
{
    __shared__ unsigned short Alds[64 * 32];
    __shared__ unsigned short Blds[64 * 32];
    const int tid = threadIdx.x;
    const int w = tid >> 6, l = tid & 63;
    const int wm = w >> 1, wn = w & 1;
    const int lane15 = l & 15, quad = l >> 4;
    const int n0 = blockIdx.x * 64;    // grid.x = 8
    const int m0 = blockIdx.y * 64;    // grid.y = 64

    const int srow = w * 16 + (l >> 2);
    const int skof = (l & 3) << 3;

    f32x4 acc[2][2];
    #pragma unroll
    for (int i = 0; i < 2; i++)
        #pragma unroll
        for (int j = 0; j < 2; j++) acc[i][j] = (f32x4){0.f, 0.f, 0.f, 0.f};

    for (int k0 = 0; k0 < DM; k0 += 32) {
        __syncthreads();
        gload16(&ctxb[(size_t)(m0 + srow) * DM + k0 + skof], (char*)Alds + w * 1024);
        gload16(&Wob[(size_t)(n0 + srow) * DM + k0 + skof],  (char*)Blds + w * 1024);
        __syncthreads();

        bf16x8 af[2], bfr[2];
        #pragma unroll
        for (int i = 0; i < 2; i++)
            af[i] = *(bf16x8*)&Alds[(wm * 32 + i * 16 + lane15) * 32 + quad * 8];
        #pragma unroll
        for (int j = 0; j < 2; j++)
            bfr[j] = *(bf16x8*)&Blds[(wn * 32 + j * 16 + lane15) * 32 + quad * 8];
        #pragma unroll
        for (int i = 0; i < 2; i++)
            #pragma unroll
            for (int j = 0; j < 2; j++)
                acc[i][j] = __builtin_amdgcn_mfma_f32_16x16x32_bf16(af[i], bfr[j], acc[i][j], 0, 0, 0);
    }

    #pragma unroll
    for (int i = 0; i < 2; i++) {
        #pragma unroll
        for (int rg = 0; rg < 4; rg++) {
            int m = m0 + wm * 32 + i * 16 + quad * 4 + rg;
            #pragma unroll
            for (int j = 0; j < 2; j++) {
                int n = n0 + wn * 32 + j * 16 + lane15;
                out[(size_t)m * DM + n] = acc[i][j][rg] + bo[n];
            }
        }
    }
}

// ---------------------------------------------------------------------------
extern "C" void kernel_launch(void* const* d_in, const int* in_sizes, int n_in,
                              void* d_out, int out_size, void* d_ws, size_t ws_size,
                              hipStream_t stream)
{
    const float* x   = (const float*)d_in[0];
    const float* Wqk = (const float*)d_in[1];
    const float* bqk = (const float*)d_in[2];
    const float* Wv  = (const float*)d_in[3];
    const float* bv  = (const float*)d_in[4];
    const float* Wo  = (const float*)d_in[5];
    const float* bo  = (const float*)d_in[6];
    float* out = (float*)d_out;

    const size_t NTOK = (size_t)B_N * S_N * DM;   // 2,097,152
    float* Asum = (float*)d_ws;                   // NTOK fp32
    float* zsum = Asum + NTOK;                    // 32768 fp32
    unsigned short* xb   = (unsigned short*)(zsum + 32768);
    unsigned short* Wqkb = xb   + NTOK;
    unsigned short* Wvb  = Wqkb + 524288;
    unsigned short* Wob  = Wvb  + 262144;
    unsigned short* qb   = Wob  + 262144;
    unsigned short* kb_  = qb   + NTOK;
    unsigned short* vtb  = kb_  + NTOK;
    unsigned short* Sptb = vtb  + NTOK;
    unsigned short* ctxb = Sptb + NTOK;

    convert_bf16  <<<dim3(3072),   256, 0, stream>>>(x, Wqk, Wv, Wo, xb, Wqkb, Wvb, Wob);
    gemm_qkv_fused<<<dim3(12, 64), 256, 0, stream>>>(xb, Wqkb, Wvb, bqk, bv, qb, kb_, vtb, Asum, zsum);
    scan_states   <<<dim3(260),    256, 0, stream>>>(Asum, zsum, Sptb);
    attn_mfma     <<<dim3(512),    256, 0, stream>>>(qb, kb_, vtb, Sptb, zsum, ctxb);
    gemm_out_mfma <<<dim3(8, 64),  256, 0, stream>>>(ctxb, Wob, bo, out);
}

// Round 8
// 113.601 us; speedup vs baseline: 2.2955x; 1.0140x over previous
//
#include <hip/hip_runtime.h>
#include <math.h>

// Problem constants
#define B_N 2
#define S_N 2048
#define DM  512
#define H_N 8
#define DH  64
#define NC  32     // number of chunks = S/64
#define CH  64     // chunk length

typedef __bf16 bf16x8 __attribute__((ext_vector_type(8)));
typedef float  f32x4  __attribute__((ext_vector_type(4)));

__device__ __forceinline__ unsigned short f2bf(float f) {
    unsigned int u = __float_as_uint(f);
    u += 0x7FFFu + ((u >> 16) & 1u);          // round-to-nearest-even
    return (unsigned short)(u >> 16);
}

__device__ __forceinline__ void gload16(const void* g, void* l) {
    __builtin_amdgcn_global_load_lds(
        (const __attribute__((address_space(1))) unsigned int*)g,
        (__attribute__((address_space(3))) unsigned int*)l, 16, 0, 0);
}

// ---------------------------------------------------------------------------
// Kernel 0: fp32 -> bf16 conversion of x, Wqk, Wv, Wo.
// ---------------------------------------------------------------------------
__global__ __launch_bounds__(256) void convert_bf16(
    const float* __restrict__ x,  const float* __restrict__ wqk,
    const float* __restrict__ wv, const float* __restrict__ wo,
    unsigned short* __restrict__ xb,  unsigned short* __restrict__ wqkb,
    unsigned short* __restrict__ wvb, unsigned short* __restrict__ wob)
{
    int gid = blockIdx.x * 256 + threadIdx.x;   // 0..786431 float4 units
    const float* src; unsigned short* dst; int off;
    if (gid < 524288)      { src = x;   dst = xb;   off = gid; }
    else if (gid < 655360) { src = wqk; dst = wqkb; off = gid - 524288; }
    else if (gid < 720896) { src = wv;  dst = wvb;  off = gid - 655360; }
    else                   { src = wo;  dst = wob;  off = gid - 720896; }
    float4 v = ((const float4*)src)[off];
    ushort4 r; r.x = f2bf(v.x); r.y = f2bf(v.y); r.z = f2bf(v.z); r.w = f2bf(v.w);
    ((ushort4*)dst)[off] = r;
}

// ---------------------------------------------------------------------------
// Kernel 1: fused projection + per-chunk state sums.  64-row m-tiles, BK=64.
// grid = (12, 64):  bx<4  -> q-blocks;  bx>=4 -> kv-blocks (head h=bx-4).
// BK=64 staged as two [64][32] (A) / [128][32] (B) sub-tiles -> fragment
// addressing identical to the proven BK=32 pattern, barrier count halved.
// ---------------------------------------------------------------------------
__global__ __launch_bounds__(256) void gemm_qkv_fused(
    const unsigned short* __restrict__ xb,
    const unsigned short* __restrict__ Wqkb,
    const unsigned short* __restrict__ Wvb,
    const float* __restrict__ bqk, const float* __restrict__ bv,
    unsigned short* __restrict__ qb, unsigned short* __restrict__ kb_,
    unsigned short* __restrict__ vtb,
    float* __restrict__ Asum, float* __restrict__ zsum)
{
    __shared__ unsigned short Alds[2 * 64 * 32];    // [half][64][32]
    __shared__ unsigned short Blds[2 * 128 * 32];   // [half][128][32]
    __shared__ unsigned short ktT[64 * 72];
    __shared__ unsigned short vtT[64 * 72];

    const int tid = threadIdx.x;
    const int w = tid >> 6, l = tid & 63;
    const int wm = w >> 1, wn = w & 1;
    const int lane15 = l & 15, quad = l >> 4;
    const int bx = blockIdx.x;
    const int m0 = blockIdx.y * 64;    // grid.y = 64
    const int isq = (bx < 4);
    const int h = isq ? 0 : (bx - 4);

    const int srow = w * 16 + (l >> 2);   // 0..63
    const int skof = (l & 3) << 3;

    f32x4 acc[2][4];
    #pragma unroll
    for (int i = 0; i < 2; i++)
        #pragma unroll
        for (int j = 0; j < 4; j++) acc[i][j] = (f32x4){0.f, 0.f, 0.f, 0.f};

    for (int k0 = 0; k0 < DM; k0 += 64) {
        __syncthreads();
        // A: two 32-k halves
        gload16(&xb[(size_t)(m0 + srow) * DM + k0 + skof],      (char*)Alds + w * 1024);
        gload16(&xb[(size_t)(m0 + srow) * DM + k0 + 32 + skof], (char*)Alds + 4096 + w * 1024);
        if (isq) {
            gload16(&Wqkb[(size_t)(bx * 128 + srow) * DM + k0 + skof],           (char*)Blds + w * 1024);
            gload16(&Wqkb[(size_t)(bx * 128 + 64 + srow) * DM + k0 + skof],      (char*)Blds + 4096 + w * 1024);
            gload16(&Wqkb[(size_t)(bx * 128 + srow) * DM + k0 + 32 + skof],      (char*)Blds + 8192 + w * 1024);
            gload16(&Wqkb[(size_t)(bx * 128 + 64 + srow) * DM + k0 + 32 + skof], (char*)Blds + 12288 + w * 1024);
        } else {
            gload16(&Wqkb[(size_t)(512 + h * 64 + srow) * DM + k0 + skof],       (char*)Blds + w * 1024);
            gload16(&Wvb[(size_t)(h * 64 + srow) * DM + k0 + skof],              (char*)Blds + 4096 + w * 1024);
            gload16(&Wqkb[(size_t)(512 + h * 64 + srow) * DM + k0 + 32 + skof],  (char*)Blds + 8192 + w * 1024);
            gload16(&Wvb[(size_t)(h * 64 + srow) * DM + k0 + 32 + skof],         (char*)Blds + 12288 + w * 1024);
        }
        __syncthreads();

        #pragma unroll
        for (int s = 0; s < 2; s++) {
            bf16x8 af[2], bfr[4];
            #pragma unroll
            for (int i = 0; i < 2; i++)
                af[i] = *(bf16x8*)&Alds[s * 2048 + (wm * 32 + i * 16 + lane15) * 32 + quad * 8];
            #pragma unroll
            for (int j = 0; j < 4; j++)
                bfr[j] = *(bf16x8*)&Blds[s * 4096 + (wn * 64 + j * 16 + lane15) * 32 + quad * 8];
            #pragma unroll
            for (int i = 0; i < 2; i++)
                #pragma unroll
                for (int j = 0; j < 4; j++)
                    acc[i][j] = __builtin_amdgcn_mfma_f32_16x16x32_bf16(af[i], bfr[j], acc[i][j], 0, 0, 0);
        }
    }

    const int bbu = m0 >> 11;          // batch index (block-uniform)
    const int t0  = m0 & (S_N - 1);    // global t of local row 0
    const int c0  = t0 >> 6;           // chunk index

    if (isq) {
        #pragma unroll
        for (int i = 0; i < 2; i++) {
            #pragma unroll
            for (int rg = 0; rg < 4; rg++) {
                int m = m0 + wm * 32 + i * 16 + quad * 4 + rg;
                int bb = m >> 11, t = m & (S_N - 1);
                #pragma unroll
                for (int j = 0; j < 4; j++) {
                    int n = bx * 128 + wn * 64 + j * 16 + lane15;   // 0..511
                    float val = acc[i][j][rg] + bqk[n];
                    val = (val > 0.f) ? (val + 1.f) : __expf(val);
                    qb[(((size_t)bb * H_N + (n >> 6)) * S_N + t) * DH + (n & 63)] = f2bf(val);
                }
            }
        }
        return;
    }

    // ---- kv epilogue: wn==0 half is k (elu+1), wn==1 half is v ----
    #pragma unroll
    for (int i = 0; i < 2; i++) {
        #pragma unroll
        for (int rg = 0; rg < 4; rg++) {
            int tl = wm * 32 + i * 16 + quad * 4 + rg;   // local row 0..63
            int t  = t0 + tl;
            #pragma unroll
            for (int j = 0; j < 4; j++) {
                int col = j * 16 + lane15;               // 0..63 within half
                if (wn == 0) {
                    float val = acc[i][j][rg] + bqk[512 + h * 64 + col];
                    val = (val > 0.f) ? (val + 1.f) : __expf(val);
                    unsigned short us = f2bf(val);
                    kb_[(((size_t)bbu * H_N + h) * S_N + t) * DH + col] = us;
                    ktT[col * 72 + tl] = us;
                } else {
                    float val = acc[i][j][rg] + bv[h * 64 + col];
                    vtT[col * 72 + tl] = f2bf(val);
                }
            }
        }
    }
    __syncthreads();

    // ---- coalesced copy vT -> vtb global [bh][d][t] ----
    {
        size_t vbase = (((size_t)bbu * H_N + h) * DH) * S_N + t0;
        #pragma unroll
        for (int it = 0; it < 2; it++) {
            int idx = it * 2048 + tid * 8;
            int d = idx >> 6, tt = idx & 63;
            *(bf16x8*)&vtb[vbase + (size_t)d * S_N + tt] = *(bf16x8*)&vtT[d * 72 + tt];
        }
    }

    // ---- St via MFMA; wave w owns d2 rows 16w..16w+15 ----
    {
        int blk = ((bbu * H_N + h) * NC) + c0;
        bf16x8 va[2];
        #pragma unroll
        for (int s = 0; s < 2; s++)
            va[s] = *(bf16x8*)&vtT[(w * 16 + lane15) * 72 + s * 32 + quad * 8];
        f32x4 sacc[4];
        #pragma unroll
        for (int j = 0; j < 4; j++) sacc[j] = (f32x4){0.f, 0.f, 0.f, 0.f};
        #pragma unroll
        for (int j = 0; j < 4; j++)
            #pragma unroll
            for (int s = 0; s < 2; s++) {
                bf16x8 kB = *(bf16x8*)&ktT[(j * 16 + lane15) * 72 + s * 32 + quad * 8];
                sacc[j] = __builtin_amdgcn_mfma_f32_16x16x32_bf16(va[s], kB, sacc[j], 0, 0, 0);
            }
        #pragma unroll
        for (int j = 0; j < 4; j++)
            #pragma unroll
            for (int rg = 0; rg < 4; rg++)
                Asum[(size_t)blk * 4096 + (w * 16 + quad * 4 + rg) * 64 + j * 16 + lane15] = sacc[j][rg];
    }

    // ---- z: threads 0..63, one d1 each ----
    if (tid < 64) {
        float z = 0.f;
        #pragma unroll
        for (int p = 0; p < 8; p++) {
            bf16x8 kk = *(bf16x8*)&ktT[tid * 72 + p * 8];
            #pragma unroll
            for (int e = 0; e < 8; e++) z += (float)kk[e];
        }
        zsum[(size_t)((bbu * H_N + h) * NC + c0) * 64 + tid] = z;
    }
}

// ---------------------------------------------------------------------------
// Kernel 2: exclusive prefix scan over chunks — register-batched.
// ---------------------------------------------------------------------------
__global__ __launch_bounds__(256) void scan_states(
    const float* __restrict__ Asum, float* __restrict__ zsum,
    unsigned short* __restrict__ Sptb)
{
    const int gid = blockIdx.x * 256 + threadIdx.x;   // 0..66559
    const int bh = gid / 4160;
    const int r  = gid % 4160;
    if (r < 4096) {
        size_t base = (size_t)bh * NC * 4096 + r;
        float vals[NC];
        #pragma unroll
        for (int c = 0; c < NC; c++) vals[c] = Asum[base + (size_t)c * 4096];
        float acc = 0.f;
        #pragma unroll
        for (int c = 0; c < NC; c++) {
            float tmp = vals[c];
            Sptb[base + (size_t)c * 4096] = f2bf(acc);
            acc += tmp;
        }
    } else {
        int d = r - 4096;
        size_t base = (size_t)bh * NC * 64 + d;
        float vals[NC];
        #pragma unroll
        for (int c = 0; c < NC; c++) vals[c] = zsum[base + (size_t)c * 64];
        float acc = 0.f;
        #pragma unroll
        for (int c = 0; c < NC; c++) {
            float tmp = vals[c];
            zsum[base + (size_t)c * 64] = acc;
            acc += tmp;
        }
    }
}

// ---------------------------------------------------------------------------
// Kernel 3: per-chunk attention, all-MFMA.
// ---------------------------------------------------------------------------
__global__ __launch_bounds__(256) void attn_mfma(
    const unsigned short* __restrict__ qb, const unsigned short* __restrict__ kb_,
    const unsigned short* __restrict__ vtb, const unsigned short* __restrict__ Sptb,
    const float* __restrict__ zsum, unsigned short* __restrict__ ctxb)
{
    __shared__ __align__(16) unsigned short P[64 * 72];
    __shared__ float nupart[64][4];

    const int blk = blockIdx.x;           // 0..511
    const int bh = blk >> 5, c = blk & 31;
    const int b = bh >> 3, h = bh & 7;
    const int tid = threadIdx.x;
    const int w = tid >> 6, l = tid & 63;
    const int lane15 = l & 15, quad = l >> 4;

    const unsigned short* qc  = qb  + (size_t)bh * S_N * DH + c * CH * DH;  // [t][d]
    const unsigned short* kc  = kb_ + (size_t)bh * S_N * DH + c * CH * DH;  // [u][d]
    const unsigned short* vtc = vtb + (size_t)bh * DH * S_N + c * CH;       // [d2][t], stride S_N
    const unsigned short* spc = Sptb + (size_t)blk * 4096;                  // [d2][d1]
    const float* zc = zsum + (size_t)blk * 64;

    bf16x8 af[2];
    #pragma unroll
    for (int s = 0; s < 2; s++)
        af[s] = *(const bf16x8*)&qc[(w * 16 + lane15) * DH + s * 32 + quad * 8];

    // scores S[t][u]
    f32x4 sacc[4];
    #pragma unroll
    for (int j = 0; j < 4; j++) sacc[j] = (f32x4){0.f, 0.f, 0.f, 0.f};
    #pragma unroll
    for (int j = 0; j < 4; j++)
        #pragma unroll
        for (int s = 0; s < 2; s++) {
            bf16x8 bk = *(const bf16x8*)&kc[(j * 16 + lane15) * DH + s * 32 + quad * 8];
            sacc[j] = __builtin_amdgcn_mfma_f32_16x16x32_bf16(af[s], bk, sacc[j], 0, 0, 0);
        }

    // causal mask + store P (bf16) to LDS
    const int r0 = w * 16 + quad * 4;
    #pragma unroll
    for (int j = 0; j < 4; j++) {
        int u = j * 16 + lane15;
        #pragma unroll
        for (int rg = 0; rg < 4; rg++) {
            int rr = r0 + rg;
            float v = (u <= rr) ? sacc[j][rg] : 0.f;
            P[rr * 72 + u] = f2bf(v);
        }
    }
    __syncthreads();

    // nu: thread (tl, part) sums P[tl][16*part..+15] + q.zprev strip
    const int tl = tid >> 2, part = tid & 3;
    float nup = 0.f;
    {
        bf16x8 p0 = *(const bf16x8*)&P[tl * 72 + part * 16];
        bf16x8 p1 = *(const bf16x8*)&P[tl * 72 + part * 16 + 8];
        bf16x8 q0 = *(const bf16x8*)&qc[tl * DH + part * 16];
        bf16x8 q1 = *(const bf16x8*)&qc[tl * DH + part * 16 + 8];
        #pragma unroll
        for (int i = 0; i < 8; i++) {
            nup += (float)p0[i] + (float)p1[i];
            nup += (float)q0[i] * zc[part * 16 + i];
            nup += (float)q1[i] * zc[part * 16 + 8 + i];
        }
    }
    nupart[tl][part] = nup;
    __syncthreads();

    // numerator: intra (P @ vt) + inter (q @ Spt), fused accumulator
    bf16x8 pa[2];
    #pragma unroll
    for (int s = 0; s < 2; s++)
        pa[s] = *(const bf16x8*)&P[(w * 16 + lane15) * 72 + s * 32 + quad * 8];

    f32x4 acc[4];
    #pragma unroll
    for (int j = 0; j < 4; j++) acc[j] = (f32x4){0.f, 0.f, 0.f, 0.f};
    #pragma unroll
    for (int j = 0; j < 4; j++)
        #pragma unroll
        for (int s = 0; s < 2; s++) {
            bf16x8 bv8 = *(const bf16x8*)&vtc[(size_t)(j * 16 + lane15) * S_N + s * 32 + quad * 8];
            acc[j] = __builtin_amdgcn_mfma_f32_16x16x32_bf16(pa[s], bv8, acc[j], 0, 0, 0);
            bf16x8 bs = *(const bf16x8*)&spc[(j * 16 + lane15) * 64 + s * 32 + quad * 8];
            acc[j] = __builtin_amdgcn_mfma_f32_16x16x32_bf16(af[s], bs, acc[j], 0, 0, 0);
        }

    // epilogue: divide by nu, write ctx bf16 [b*S+t][DM]
    #pragma unroll
    for (int rg = 0; rg < 4; rg++) {
        int rr = r0 + rg;
        float nu = nupart[rr][0] + nupart[rr][1] + nupart[rr][2] + nupart[rr][3];
        float inv = 1.f / nu;
        size_t obase = ((size_t)b * S_N + c * CH + rr) * DM + h * DH;
        #pragma unroll
        for (int j = 0; j < 4; j++)
            ctxb[obase + j * 16 + lane15] = f2bf(acc[j][rg] * inv);
    }
}

// ---------------------------------------------------------------------------
// Kernel 4: output projection via bf16 MFMA.  64x64 tiles, BK=64, grid (8,64).
// ---------------------------------------------------------------------------
__global__ __launch_bounds__(256) void gemm_out_mfma(
    const unsigned short* __restrict__ ctxb,
    const unsigned short* __restrict__ Wob,
    const float* __restrict__ bo, float* __restrict__ out)
{
    __shared__ unsigned short Alds[2 * 64 * 32];
    __shared__ unsigned short Blds[2 * 64 * 32];
    const int tid = threadIdx.x;
    const int w = tid >> 6, l = tid & 63;
    const int wm = w >> 1, wn = w & 1;
    const int lane15 = l & 15, quad = l >> 4;
    const int n0 = blockIdx.x * 64;    // grid.x = 8
    const int m0 = blockIdx.y * 64;    // grid.y = 64

    const int srow = w * 16 + (l >> 2);
    const int skof = (l & 3) << 3;

    f32x4 acc[2][2];
    #pragma unroll
    for (int i = 0; i < 2; i++)
        #pragma unroll
        for (int j = 0; j < 2; j++) acc[i][j] = (f32x4){0.f, 0.f, 0.f, 0.f};

    for (int k0 = 0; k0 < DM; k0 += 64) {
        __syncthreads();
        gload16(&ctxb[(size_t)(m0 + srow) * DM + k0 + skof],      (char*)Alds + w * 1024);
        gload16(&ctxb[(size_t)(m0 + srow) * DM + k0 + 32 + skof], (char*)Alds + 4096 + w * 1024);
        gload16(&Wob[(size_t)(n0 + srow) * DM + k0 + skof],       (char*)Blds + w * 1024);
        gload16(&Wob[(size_t)(n0 + srow) * DM + k0 + 32 + skof],  (char*)Blds + 4096 + w * 1024);
        __syncthreads();

        #pragma unroll
        for (int s = 0; s < 2; s++) {
            bf16x8 af2[2], bfr[2];
            #pragma unroll
            for (int i = 0; i < 2; i++)
                af2[i] = *(bf16x8*)&Alds[s * 2048 + (wm * 32 + i * 16 + lane15) * 32 + quad * 8];
            #pragma unroll
            for (int j = 0; j < 2; j++)
                bfr[j] = *(bf16x8*)&Blds[s * 2048 + (wn * 32 + j * 16 + lane15) * 32 + quad * 8];
            #pragma unroll
            for (int i = 0; i < 2; i++)
                #pragma unroll
                for (int j = 0; j < 2; j++)
                    acc[i][j] = __builtin_amdgcn_mfma_f32_16x16x32_bf16(af2[i], bfr[j], acc[i][j], 0, 0, 0);
        }
    }

    #pragma unroll
    for (int i = 0; i < 2; i++) {
        #pragma unroll
        for (int rg = 0; rg < 4; rg++) {
            int m = m0 + wm * 32 + i * 16 + quad * 4 + rg;
            #pragma unroll
            for (int j = 0; j < 2; j++) {
                int n = n0 + wn * 32 + j * 16 + lane15;
                out[(size_t)m * DM + n] = acc[i][j][rg] + bo[n];
            }
        }
    }
}

// ---------------------------------------------------------------------------
extern "C" void kernel_launch(void* const* d_in, const int* in_sizes, int n_in,
                              void* d_out, int out_size, void* d_ws, size_t ws_size,
                              hipStream_t stream)
{
    const float* x   = (const float*)d_in[0];
    const float* Wqk = (const float*)d_in[1];
    const float* bqk = (const float*)d_in[2];
    const float* Wv  = (const float*)d_in[3];
    const float* bv  = (const float*)d_in[4];
    const float* Wo  = (const float*)d_in[5];
    const float* bo  = (const float*)d_in[6];
    float* out = (float*)d_out;

    const size_t NTOK = (size_t)B_N * S_N * DM;   // 2,097,152
    float* Asum = (float*)d_ws;                   // NTOK fp32
    float* zsum = Asum + NTOK;                    // 32768 fp32
    unsigned short* xb   = (unsigned short*)(zsum + 32768);
    unsigned short* Wqkb = xb   + NTOK;
    unsigned short* Wvb  = Wqkb + 524288;
    unsigned short* Wob  = Wvb  + 262144;
    unsigned short* qb   = Wob  + 262144;
    unsigned short* kb_  = qb   + NTOK;
    unsigned short* vtb  = kb_  + NTOK;
    unsigned short* Sptb = vtb  + NTOK;
    unsigned short* ctxb = Sptb + NTOK;

    convert_bf16  <<<dim3(3072),   256, 0, stream>>>(x, Wqk, Wv, Wo, xb, Wqkb, Wvb, Wob);
    gemm_qkv_fused<<<dim3(12, 64), 256, 0, stream>>>(xb, Wqkb, Wvb, bqk, bv, qb, kb_, vtb, Asum, zsum);
    scan_states   <<<dim3(260),    256, 0, stream>>>(Asum, zsum, Sptb);
    attn_mfma     <<<dim3(512),    256, 0, stream>>>(qb, kb_, vtb, Sptb, zsum, ctxb);
    gemm_out_mfma <<<dim3(8, 64),  256, 0, stream>>>(ctxb, Wob, bo, out);
}